// Round 3
// 639.170 us; speedup vs baseline: 1.0084x; 1.0084x over previous
//
#include <hip/hip_runtime.h>
#include <hip/hip_bf16.h>
#include <stdint.h>

// R5 == R3 resubmit #2 (rounds 1-2 died at broker/container level; kernel never
// executed — no compile error, no test failure. Source audited for hang/OOB:
// none constructible. Same LDS/block/grid envelope as the verified R2 run.)
// R3: overlap + XCD locality for the main layer kernel.
// - LDS was silently duplicated (shared arrays inside the twice-inlined impl):
//   104 KB reported for a 52 KB working set. Hoisted to kernel scope and used
//   as a TRUE double buffer (2x At + 2x Wt = 104 KB).
// - Register-staged prefetch: per step, issue next step's global loads right
//   after the single barrier, compute current step from LDS, then write regs
//   to the other buffer. Loads overlap compute + wait. One barrier per step.
// - XCD co-location swizzle: blocks sharing a dg-pair's W 64B sectors and the
//   same dg's A rows (2 sub-d x 4 o-groups) are placed == mod 8 -> same XCD.
//   Kills the ~2x W sector over-fetch and cross-XCD A re-fetch.
// - launch_bounds(256,1): the old (256,2) couldn't co-schedule 2 blocks at
//   104 KB LDS anyway; it only capped the register allocator.
// Everything else (l0, fin, tail, epi, launcher, WS layout) unchanged.

typedef __attribute__((ext_vector_type(4))) float floatx4;
typedef __attribute__((ext_vector_type(8))) short shortx8;

__device__ __forceinline__ float bf2f(unsigned short u){
    union { unsigned int u; float f; } c; c.u = ((unsigned int)u) << 16; return c.f;
}
__device__ __forceinline__ unsigned short f2bf(float f){
    union { float f; unsigned int u; } c; c.f = f;
    unsigned int x = c.u;
    x += 0x7FFFu + ((x >> 16) & 1u);
    return (unsigned short)(x >> 16);
}

// ---------------------------------------------------------------------------
// dtype probe (unchanged, verified working)
__global__ void probe_kernel(const unsigned int* __restrict__ x, int* __restrict__ flag){
    __shared__ int cnt[256];
    int tid = threadIdx.x;
    unsigned short lo = (unsigned short)(x[tid] & 0xFFFFu);
    int e = (lo >> 7) & 0xFF;
    cnt[tid] = (e >= 90 && e <= 143) ? 1 : 0;
    __syncthreads();
    for (int s = 128; s > 0; s >>= 1){
        if (tid < s) cnt[tid] += cnt[tid + s];
        __syncthreads();
    }
    if (tid == 0) *flag = (cnt[0] > 160) ? 1 : 0;
}

// ---------------------------------------------------------------------------
// Layer 0: A1[p=d][b][o] = relu(sum_{c,t} x[b,c,2d+t]*w0[o,c,d,t]) * (1/sqrt(3))
__global__ __launch_bounds__(256) void l0_kernel(const int* __restrict__ flag,
        const void* __restrict__ xv, const void* __restrict__ wv,
        unsigned short* __restrict__ A1){
    __shared__ float Xs[128*6];
    const int d = blockIdx.x;
    const int tid = threadIdx.x;
    const bool BF = (*flag != 0);
    for (int i = tid; i < 384; i += 256){
        int b = i / 3, c = i - b*3;
        if (BF){
            unsigned int u = *(const unsigned int*)((const unsigned short*)xv + (b*3+c)*1024 + 2*d);
            Xs[b*6 + c*2]     = bf2f((unsigned short)(u & 0xFFFFu));
            Xs[b*6 + c*2 + 1] = bf2f((unsigned short)(u >> 16));
        } else {
            const float* xf = (const float*)xv + (b*3+c)*1024 + 2*d;
            Xs[b*6 + c*2] = xf[0]; Xs[b*6 + c*2 + 1] = xf[1];
        }
    }
    __syncthreads();
    const int o = tid;
    float wr[6];
    #pragma unroll
    for (int c = 0; c < 3; ++c){
        if (BF){
            unsigned int u = *(const unsigned int*)((const unsigned short*)wv + ((o*3+c)*512 + d)*2);
            wr[c*2]   = bf2f((unsigned short)(u & 0xFFFFu));
            wr[c*2+1] = bf2f((unsigned short)(u >> 16));
        } else {
            const float* wf = (const float*)wv + ((o*3+c)*512 + d)*2;
            wr[c*2] = wf[0]; wr[c*2+1] = wf[1];
        }
    }
    const float s3 = 0.57735026918962576f;
    for (int b = 0; b < 128; ++b){
        float s = 0.f;
        #pragma unroll
        for (int j = 0; j < 6; ++j) s += Xs[b*6 + j] * wr[j];
        A1[d*32768 + b*256 + o] = f2bf(fmaxf(s, 0.f) * s3);
    }
}

// ---------------------------------------------------------------------------
// Main layer kernel. Logical block = (d-group of 4, o-group of 64, k-slice).
// Wave <-> d within the group. Double-buffered LDS, register-staged prefetch.
// k-order within a K=32 MFMA step: k = t*16 + c_local.
template<bool WBF, bool ATOMIC>
__device__ __forceinline__ void layer_main_impl(const unsigned short* __restrict__ Ain,
        const void* __restrict__ wv, void* __restrict__ out, int dl, int ks,
        unsigned short* __restrict__ At0, unsigned short* __restrict__ At1,
        unsigned short* __restrict__ Wt0, unsigned short* __restrict__ Wt1){
    const int tid  = threadIdx.x;
    const int lane = tid & 63, wv_ = tid >> 6;
    const int g = lane >> 4, mr = lane & 15;
    const int nd = dl >> 2;

    // XCD co-location swizzle: the 8 blocks {dg-pair x 4 o-groups} that share
    // W 64B sectors / A rows are placed == mod 8 -> same XCD L2.
    int dg, ng, ksid;
    {
        const int bi = blockIdx.x;
        const int G  = gridDim.x;
        if (nd >= 2 && (G & 63) == 0){
            const int x = bi & 7, e = (bi >> 3) & 7, gg = bi >> 6;
            const int pid = gg*8 + x;          // [0, G/8)
            const int nd2 = nd >> 1;
            dg   = (pid % nd2)*2 + (e & 1);
            ng   = e >> 1;
            ksid = pid / nd2;
        } else {
            dg = bi % nd; const int r = bi / nd; ng = r & 3; ksid = r >> 2;
        }
    }
    const int TS = 16 / ks;
    const int d0 = dg << 2;
    const int o0 = ng << 6;
    const int dme = d0 + wv_;
    const float* wF = (const float*)wv;
    const unsigned short* wB = (const unsigned short*)wv;
    const int sb = tid >> 1, sh = tid & 1;      // A staging coords

    floatx4 acc[8][4];
    #pragma unroll
    for (int m = 0; m < 8; ++m)
        #pragma unroll
        for (int nb = 0; nb < 4; ++nb)
            acc[m][nb] = (floatx4){0.f,0.f,0.f,0.f};

    uint4  aR[8];                 // A prefetch regs (128 B/thread)
    uint4  wRu[4];                // W prefetch regs, bf16 path
    float4 wRa[4], wRb[4];        // W prefetch regs, fp32 path

    auto LOADS = [&](int s){
        const int c0 = (ksid*TS + s) << 4;
        #pragma unroll
        for (int i = 0; i < 8; ++i)
            aR[i] = *(const uint4*)(Ain + (2*d0 + i)*32768 + sb*256 + c0 + sh*8);
        #pragma unroll
        for (int rr = 0; rr < 4; ++rr){
            const int run = (rr << 8) + tid;
            const int oo = run >> 4, cl = run & 15;
            const int src = ((((o0 + oo) << 8) + (c0 + cl))*dl + d0)*2;
            if (WBF){
                wRu[rr] = *(const uint4*)(wB + src);
            } else {
                wRa[rr] = *(const float4*)(wF + src);
                wRb[rr] = *(const float4*)(wF + src + 4);
            }
        }
    };
    auto WRITES = [&](unsigned short* At, unsigned short* Wt){
        #pragma unroll
        for (int i = 0; i < 8; ++i)
            *(uint4*)(At + (i*128 + sb)*16 + sh*8) = aR[i];
        #pragma unroll
        for (int rr = 0; rr < 4; ++rr){
            const int run = (rr << 8) + tid;
            const int oo = run >> 4, cl = run & 15;
            unsigned short wtmp[8];
            if (WBF){
                const unsigned short* pu = (const unsigned short*)&wRu[rr];
                #pragma unroll
                for (int j = 0; j < 8; ++j) wtmp[j] = pu[j];
            } else {
                wtmp[0]=f2bf(wRa[rr].x); wtmp[1]=f2bf(wRa[rr].y);
                wtmp[2]=f2bf(wRa[rr].z); wtmp[3]=f2bf(wRa[rr].w);
                wtmp[4]=f2bf(wRb[rr].x); wtmp[5]=f2bf(wRb[rr].y);
                wtmp[6]=f2bf(wRb[rr].z); wtmp[7]=f2bf(wRb[rr].w);
            }
            #pragma unroll
            for (int j = 0; j < 8; ++j){
                const int dd = j >> 1, t = j & 1;
                Wt[(dd*64 + oo)*40 + t*16 + cl] = wtmp[j];
            }
        }
    };

    // prologue: fill buffer 0
    LOADS(0);
    WRITES(At0, Wt0);
    for (int s = 0; s < TS; ++s){
        __syncthreads();                       // buf[s&1] writes visible; prev reads done
        if (s + 1 < TS) LOADS(s + 1);          // prefetch in flight during compute
        const unsigned short* At = (s & 1) ? At1 : At0;
        const unsigned short* Wt = (s & 1) ? Wt1 : Wt0;
        shortx8 bfr[4];
        #pragma unroll
        for (int nb = 0; nb < 4; ++nb)
            bfr[nb] = *(const shortx8*)(Wt + (wv_*64 + nb*16 + mr)*40 + g*8);
        #pragma unroll
        for (int m = 0; m < 8; ++m){
            shortx8 af = *(const shortx8*)(At + ((wv_*2 + (g>>1))*128 + m*16 + mr)*16 + (g&1)*8);
            #pragma unroll
            for (int nb = 0; nb < 4; ++nb)
                acc[m][nb] = __builtin_amdgcn_mfma_f32_16x16x32_bf16(af, bfr[nb], acc[m][nb], 0,0,0);
        }
        if (s + 1 < TS) WRITES((s & 1) ? At0 : At1, (s & 1) ? Wt0 : Wt1);
    }
    // epilogue: D row=g*4+r -> b, col=mr -> o
    #pragma unroll
    for (int m = 0; m < 8; ++m)
        #pragma unroll
        for (int nb = 0; nb < 4; ++nb)
            #pragma unroll
            for (int r = 0; r < 4; ++r){
                const int bb = m*16 + g*4 + r;
                const int oc = o0 + nb*16 + mr;
                if (ATOMIC)
                    unsafeAtomicAdd((float*)out + (dme*128 + bb)*256 + oc, acc[m][nb][r]);
                else
                    ((unsigned short*)out)[dme*32768 + bb*256 + oc] =
                        f2bf(fmaxf(acc[m][nb][r], 0.f) * 0.0625f);
            }
}

template<bool ATOMIC>
__global__ __launch_bounds__(256,1) void layer_main_k(const int* __restrict__ flag,
        const unsigned short* __restrict__ Ain, const void* __restrict__ wv,
        void* __restrict__ out, int dl, int ks){
    // hoisted: ONE allocation shared by both dtype branches (was duplicated),
    // now used as a real double buffer. 2*(32 KB) + 2*(20 KB) = 104 KB.
    __shared__ unsigned short At[2][8*128*16];
    __shared__ unsigned short Wt[2][4*64*40];
    if (*flag) layer_main_impl<true,  ATOMIC>(Ain, wv, out, dl, ks, At[0], At[1], Wt[0], Wt[1]);
    else       layer_main_impl<false, ATOMIC>(Ain, wv, out, dl, ks, At[0], At[1], Wt[0], Wt[1]);
}

// ---------------------------------------------------------------------------
// Tail layers (dl<=2): direct gather (weights ~1MB, L2-resident), atomic fp32 out.
// k-order c-minor: k = c*2 + t.
template<bool WBF>
__device__ __forceinline__ void tail_impl(const unsigned short* __restrict__ Ain,
        const void* __restrict__ wv, float* __restrict__ outS, int dl, int ksplit){
    int id = blockIdx.x;
    int d = id % dl; int t2 = id / dl;
    int ob = t2 & 3; int ksid = t2 >> 2;
    const int KSEG = 512 / ksplit;
    const int k0s = ksid * KSEG;
    const int lane = threadIdx.x & 63, wv2 = threadIdx.x >> 6;
    const int mr = lane & 15, kg = lane >> 4;
    const float* wF = (const float*)wv;
    const unsigned short* wB = (const unsigned short*)wv;
    floatx4 acc[2][4];
    #pragma unroll
    for (int mi = 0; mi < 2; ++mi)
        #pragma unroll
        for (int ni = 0; ni < 4; ++ni) acc[mi][ni] = (floatx4){0.f,0.f,0.f,0.f};
    for (int k0 = k0s; k0 < k0s + KSEG; k0 += 32){
        int c0 = (k0 >> 1) + kg*4;
        shortx8 af[2];
        #pragma unroll
        for (int mi = 0; mi < 2; ++mi){
            int b = wv2*32 + mi*16 + mr;
            #pragma unroll
            for (int cc = 0; cc < 4; ++cc){
                af[mi][2*cc]   = (short)Ain[(2*d)*32768   + b*256 + c0 + cc];
                af[mi][2*cc+1] = (short)Ain[(2*d+1)*32768 + b*256 + c0 + cc];
            }
        }
        shortx8 bf_[4];
        #pragma unroll
        for (int ni = 0; ni < 4; ++ni){
            int o = ob*64 + ni*16 + mr;
            int base = ((o*256 + c0)*dl + d)*2;
            #pragma unroll
            for (int cc = 0; cc < 4; ++cc){
                if (WBF){
                    unsigned int u = *(const unsigned int*)(wB + base);
                    bf_[ni][2*cc]   = (short)(u & 0xFFFFu);
                    bf_[ni][2*cc+1] = (short)(u >> 16);
                } else {
                    bf_[ni][2*cc]   = (short)f2bf(wF[base]);
                    bf_[ni][2*cc+1] = (short)f2bf(wF[base+1]);
                }
                base += 2*dl;
            }
        }
        #pragma unroll
        for (int mi = 0; mi < 2; ++mi)
            #pragma unroll
            for (int ni = 0; ni < 4; ++ni)
                acc[mi][ni] = __builtin_amdgcn_mfma_f32_16x16x32_bf16(af[mi], bf_[ni], acc[mi][ni], 0,0,0);
    }
    #pragma unroll
    for (int mi = 0; mi < 2; ++mi)
        #pragma unroll
        for (int ni = 0; ni < 4; ++ni)
            #pragma unroll
            for (int r = 0; r < 4; ++r){
                int b = wv2*32 + mi*16 + kg*4 + r;
                int o = ob*64 + ni*16 + mr;
                unsafeAtomicAdd(outS + (d*128 + b)*256 + o, acc[mi][ni][r]);
            }
}
__global__ __launch_bounds__(256) void tail_k(const int* __restrict__ flag,
        const unsigned short* __restrict__ Ain, const void* __restrict__ wv,
        float* __restrict__ outS, int dl, int ksplit){
    if (*flag) tail_impl<true >(Ain, wv, outS, dl, ksplit);
    else       tail_impl<false>(Ain, wv, outS, dl, ksplit);
}

// ---------------------------------------------------------------------------
// Finalize: A_{l+1}[i] = bf16(relu(S_l[i]) / 16)   (identity index map)
__global__ __launch_bounds__(256) void fin_kernel(const float* __restrict__ S,
        unsigned short* __restrict__ A, int n){
    int i = (blockIdx.x*256 + threadIdx.x)*4;
    if (i + 3 < n){
        float4 v = *(const float4*)(S + i);
        unsigned short r0 = f2bf(fmaxf(v.x,0.f)*0.0625f);
        unsigned short r1 = f2bf(fmaxf(v.y,0.f)*0.0625f);
        unsigned short r2 = f2bf(fmaxf(v.z,0.f)*0.0625f);
        unsigned short r3 = f2bf(fmaxf(v.w,0.f)*0.0625f);
        unsigned int lo = (unsigned int)r0 | ((unsigned int)r1 << 16);
        unsigned int hi = (unsigned int)r2 | ((unsigned int)r3 << 16);
        uint2 u; u.x = lo; u.y = hi;
        *(uint2*)(A + i) = u;
    }
}

// ---------------------------------------------------------------------------
// Epilogue (verified): out[b,o] = (sum_h relu(S9[b,h])/16 * beta[h,o]) / 256
template<bool BF>
__device__ __forceinline__ void epi_impl(const float* __restrict__ S9, const void* __restrict__ beta,
                                         void* __restrict__ out){
    int b = blockIdx.x;
    int lane = threadIdx.x;
    float accv[10];
    #pragma unroll
    for (int o = 0; o < 10; ++o) accv[o] = 0.f;
    for (int h = lane; h < 256; h += 64){
        float y = fmaxf(S9[b*256 + h], 0.f) * 0.0625f;
        #pragma unroll
        for (int o = 0; o < 10; ++o){
            float be = BF ? bf2f(((const unsigned short*)beta)[h*10 + o])
                          : ((const float*)beta)[h*10 + o];
            accv[o] += y * be;
        }
    }
    #pragma unroll
    for (int off = 32; off > 0; off >>= 1){
        #pragma unroll
        for (int o = 0; o < 10; ++o)
            accv[o] += __shfl_down(accv[o], off, 64);
    }
    if (lane == 0){
        #pragma unroll
        for (int o = 0; o < 10; ++o){
            float v = accv[o] * (1.f/256.f);
            if (BF) ((unsigned short*)out)[b*10 + o] = f2bf(v);
            else    ((float*)out)[b*10 + o] = v;
        }
    }
}
__global__ void epi_kernel(const int* __restrict__ flag, const float* __restrict__ S9,
                           const void* __restrict__ beta, void* __restrict__ out){
    if (*flag) epi_impl<true>(S9, beta, out);
    else       epi_impl<false>(S9, beta, out);
}

// ---------------------------------------------------------------------------
extern "C" void kernel_launch(void* const* d_in, const int* in_sizes, int n_in,
                              void* d_out, int out_size, void* d_ws, size_t ws_size,
                              hipStream_t stream) {
    (void)in_sizes; (void)n_in; (void)out_size; (void)ws_size;
    char* wsb = (char*)d_ws;
    int* flag = (int*)wsb;
    // region1: A1, later overwritten by S2..S9 (fp32)
    unsigned short* A1 = (unsigned short*)(wsb + 512);
    float* S2 = (float*)(wsb + 512);
    float* S3 = S2 + 4194304;
    float* S4 = S3 + 2097152;
    float* S5 = S4 + 1048576;
    float* S6 = S5 + 524288;
    float* S7 = S6 + 262144;
    float* S8 = S7 + 131072;
    float* S9 = S8 + 65536;
    // region2: A2, later overlaid by A3..A9
    unsigned short* A2 = (unsigned short*)(wsb + 512 + 33554432);
    unsigned short* A3 = A2;
    unsigned short* A4 = A3 + 4194304;
    unsigned short* A5 = A4 + 2097152;
    unsigned short* A6 = A5 + 1048576;
    unsigned short* A7 = A6 + 524288;
    unsigned short* A8 = A7 + 262144;
    unsigned short* A9 = A8 + 131072;

    probe_kernel<<<1, 256, 0, stream>>>((const unsigned int*)d_in[0], flag);
    l0_kernel<<<512, 256, 0, stream>>>(flag, d_in[0], d_in[1], A1);
    // l1: reads A1 (region1), writes bf16 A2 (region2) -- ks=1, non-atomic
    layer_main_k<false><<<256, 256, 0, stream>>>(flag, A1, d_in[2], A2, 256, 1);
    // A1 now dead: zero S region (covers S2..S9) for atomic layers
    hipMemsetAsync(S2, 0, 33423360, stream);
    layer_main_k<true ><<<256, 256, 0, stream>>>(flag, A2, d_in[3], S2, 128, 2);
    fin_kernel<<<4096, 256, 0, stream>>>(S2, A3, 4194304);
    layer_main_k<true ><<<256, 256, 0, stream>>>(flag, A3, d_in[4], S3, 64, 4);
    fin_kernel<<<2048, 256, 0, stream>>>(S3, A4, 2097152);
    layer_main_k<true ><<<256, 256, 0, stream>>>(flag, A4, d_in[5], S4, 32, 8);
    fin_kernel<<<1024, 256, 0, stream>>>(S4, A5, 1048576);
    layer_main_k<true ><<<256, 256, 0, stream>>>(flag, A5, d_in[6], S5, 16, 16);
    fin_kernel<<<512, 256, 0, stream>>>(S5, A6, 524288);
    layer_main_k<true ><<<128, 256, 0, stream>>>(flag, A6, d_in[7], S6, 8, 16);
    fin_kernel<<<256, 256, 0, stream>>>(S6, A7, 262144);
    layer_main_k<true ><<<64, 256, 0, stream>>>(flag, A7, d_in[8], S7, 4, 16);
    fin_kernel<<<128, 256, 0, stream>>>(S7, A8, 131072);
    tail_k<<<128, 256, 0, stream>>>(flag, A8, d_in[9], S8, 2, 16);
    fin_kernel<<<64, 256, 0, stream>>>(S8, A9, 65536);
    tail_k<<<64, 256, 0, stream>>>(flag, A9, d_in[10], S9, 1, 16);
    epi_kernel<<<128, 64, 0, stream>>>(flag, S9, d_in[11], d_out);
}

// Round 4
// 635.261 us; speedup vs baseline: 1.0146x; 1.0062x over previous
//
#include <hip/hip_runtime.h>
#include <hip/hip_bf16.h>
#include <stdint.h>

// R6: kill PromoteAlloca + A-direct + m-split occupancy.
// R3 post-mortem: LDS_Block_Size 139264 = declared 106496 + 32768 — the aR[8]
// prefetch array (256 thr x 128 B) was promoted to LDS by AMDGPUPromoteAlloca.
// LDS-resident per-thread arrays are addressed lane*128+i*16 -> all 64 lanes on
// ONE bank = 64-way conflict (SQ_LDS_BANK_CONFLICT 262K -> 11.04M, BW fell to
// 1.45 TB/s). Fixes:
// - A staging through LDS removed entirely: each wave's A rows are private
//   (p = 2*dme + (g>>1)), and the MFMA A-frag is directly loadable from global
//   as a 16B/lane read (32B-chunk coalesced, A is L3-resident: R3 FETCH=149MB
//   ~= W-only). No At buffer, no aR array, no At read conflicts.
// - Every global-load destination is an individually NAMED register
//   (a0..a3/n0..n3, u0..u3, wa0..wa3/wb0..wb3) — nothing for PromoteAlloca.
// - LDS now Wt only: 2 x 20 KB = 40 KB -> 2 blocks/CU. M split in half
//   (block does 64 b-rows, acc[4][4]) -> grid x2 -> 8 waves/CU.
// - XCD swizzle extended: {dg-pair x 4 ng x 2 mh} = 16 blocks congruent mod 8
//   (same XCD L2); bijective for all main-layer grids (G % 128 == 0).
// Everything else (probe, l0, fin, tail, epi, WS layout) unchanged.

typedef __attribute__((ext_vector_type(4))) float floatx4;
typedef __attribute__((ext_vector_type(8))) short shortx8;

__device__ __forceinline__ float bf2f(unsigned short u){
    union { unsigned int u; float f; } c; c.u = ((unsigned int)u) << 16; return c.f;
}
__device__ __forceinline__ unsigned short f2bf(float f){
    union { float f; unsigned int u; } c; c.f = f;
    unsigned int x = c.u;
    x += 0x7FFFu + ((x >> 16) & 1u);
    return (unsigned short)(x >> 16);
}

// ---------------------------------------------------------------------------
// dtype probe (unchanged, verified working)
__global__ void probe_kernel(const unsigned int* __restrict__ x, int* __restrict__ flag){
    __shared__ int cnt[256];
    int tid = threadIdx.x;
    unsigned short lo = (unsigned short)(x[tid] & 0xFFFFu);
    int e = (lo >> 7) & 0xFF;
    cnt[tid] = (e >= 90 && e <= 143) ? 1 : 0;
    __syncthreads();
    for (int s = 128; s > 0; s >>= 1){
        if (tid < s) cnt[tid] += cnt[tid + s];
        __syncthreads();
    }
    if (tid == 0) *flag = (cnt[0] > 160) ? 1 : 0;
}

// ---------------------------------------------------------------------------
// Layer 0: A1[p=d][b][o] = relu(sum_{c,t} x[b,c,2d+t]*w0[o,c,d,t]) * (1/sqrt(3))
__global__ __launch_bounds__(256) void l0_kernel(const int* __restrict__ flag,
        const void* __restrict__ xv, const void* __restrict__ wv,
        unsigned short* __restrict__ A1){
    __shared__ float Xs[128*6];
    const int d = blockIdx.x;
    const int tid = threadIdx.x;
    const bool BF = (*flag != 0);
    for (int i = tid; i < 384; i += 256){
        int b = i / 3, c = i - b*3;
        if (BF){
            unsigned int u = *(const unsigned int*)((const unsigned short*)xv + (b*3+c)*1024 + 2*d);
            Xs[b*6 + c*2]     = bf2f((unsigned short)(u & 0xFFFFu));
            Xs[b*6 + c*2 + 1] = bf2f((unsigned short)(u >> 16));
        } else {
            const float* xf = (const float*)xv + (b*3+c)*1024 + 2*d;
            Xs[b*6 + c*2] = xf[0]; Xs[b*6 + c*2 + 1] = xf[1];
        }
    }
    __syncthreads();
    const int o = tid;
    float wr[6];
    #pragma unroll
    for (int c = 0; c < 3; ++c){
        if (BF){
            unsigned int u = *(const unsigned int*)((const unsigned short*)wv + ((o*3+c)*512 + d)*2);
            wr[c*2]   = bf2f((unsigned short)(u & 0xFFFFu));
            wr[c*2+1] = bf2f((unsigned short)(u >> 16));
        } else {
            const float* wf = (const float*)wv + ((o*3+c)*512 + d)*2;
            wr[c*2] = wf[0]; wr[c*2+1] = wf[1];
        }
    }
    const float s3 = 0.57735026918962576f;
    for (int b = 0; b < 128; ++b){
        float s = 0.f;
        #pragma unroll
        for (int j = 0; j < 6; ++j) s += Xs[b*6 + j] * wr[j];
        A1[d*32768 + b*256 + o] = f2bf(fmaxf(s, 0.f) * s3);
    }
}

// ---------------------------------------------------------------------------
// Main layer kernel. Logical block = (dg: d-group of 4, ng: o-group of 64,
// mh: batch half of 64, ksid: k-slice). Wave <-> d. A read direct from global
// (wave-private rows); W staged through double-buffered LDS (transpose).
// k-order within a K=32 MFMA step: k = t*16 + c_local (t = g>>1, c = (g&1)*8+j).
template<bool WBF, bool ATOMIC>
__device__ __forceinline__ void layer_main_impl(const unsigned short* __restrict__ Ain,
        const void* __restrict__ wv, void* __restrict__ out, int dl, int ks,
        unsigned short* __restrict__ Wt0, unsigned short* __restrict__ Wt1){
    const int tid  = threadIdx.x;
    const int lane = tid & 63, wv_ = tid >> 6;
    const int g = lane >> 4, mr = lane & 15;
    const int nd = dl >> 2;

    // XCD co-location: 16 blocks {dg&1 x ng x mh} sharing W sectors / A rows
    // placed == mod 8 -> same XCD. Bijective when nd>=2 and G%128==0.
    int dg, ng, mh, ksid;
    {
        const int bi = blockIdx.x;
        const int G  = gridDim.x;
        if (nd >= 2 && (G & 127) == 0){
            const int x = bi & 7, j = (bi >> 3) & 15, gg = bi >> 7;
            const int pid = gg*8 + x;          // [0, nd2*ks)
            const int nd2 = nd >> 1;
            dg   = (pid % nd2)*2 + (j & 1);
            ng   = (j >> 1) & 3;
            mh   = j >> 3;
            ksid = pid / nd2;
        } else {
            dg = bi % nd; const int r = bi / nd;
            ng = r & 3; mh = (r >> 2) & 1; ksid = r >> 3;
        }
    }
    const int TS = 16 / ks;
    const int d0 = dg << 2;
    const int o0 = ng << 6;
    const int b0 = mh << 6;
    const int dme = d0 + wv_;
    const float* wF = (const float*)wv;
    const unsigned short* wB = (const unsigned short*)wv;

    // ---- W staging addressing (per-thread): cl = c_local, oo_rr = rr*16 + tid>>4
    const int cl  = tid & 15;
    const int ooB = tid >> 4;                  // oo for rr=0 (local o in [0,64))
    // element index of (o0+oo, c=cl, d0, t=0): ((o*256 + c)*dl + d0)*2
    const int ws0 = (((o0 + ooB      )*256 + cl)*dl + d0)*2;
    const int ws1 = (((o0 + ooB + 16 )*256 + cl)*dl + d0)*2;
    const int ws2 = (((o0 + ooB + 32 )*256 + cl)*dl + d0)*2;
    const int ws3 = (((o0 + ooB + 48 )*256 + cl)*dl + d0)*2;
    const int wcstep = 32*dl;                  // element delta for c0 += 16

    // ---- A direct-load base: p = 2*dme + (g>>1), b = b0 + m*16 + mr,
    //      c = c0 + (g&1)*8 + j   (matches k = t*16 + c_local with t = g>>1)
    const unsigned short* Ab = Ain + (2*dme + (g>>1))*32768 + (b0 + mr)*256 + (g&1)*8;
    const int c_base = ksid*TS;                // in 16-c units

    floatx4 acc[4][4];
    #pragma unroll
    for (int m = 0; m < 4; ++m)
        #pragma unroll
        for (int nb = 0; nb < 4; ++nb)
            acc[m][nb] = (floatx4){0.f,0.f,0.f,0.f};

    // ---- named prefetch registers (NO arrays -> no PromoteAlloca)
    shortx8 a0, a1, a2, a3;        // current A frags
    shortx8 n0, n1, n2, n3;        // next A frags
    uint4  u0, u1, u2, u3;         // W stage, bf16 path
    float4 wa0, wa1, wa2, wa3;     // W stage, fp32 path (lo half)
    float4 wb0, wb1, wb2, wb3;     //                    (hi half)

#define LOADA4(d0_,d1_,d2_,d3_,s_) do { \
    const unsigned short* _p = Ab + ((c_base + (s_)) << 4); \
    d0_ = *(const shortx8*)(_p);          \
    d1_ = *(const shortx8*)(_p + 4096);   \
    d2_ = *(const shortx8*)(_p + 8192);   \
    d3_ = *(const shortx8*)(_p + 12288);  \
} while(0)

#define LOADW(s_) do { \
    const int _c = (c_base + (s_)) * wcstep; \
    if (WBF){ \
        u0 = *(const uint4*)(wB + ws0 + _c); \
        u1 = *(const uint4*)(wB + ws1 + _c); \
        u2 = *(const uint4*)(wB + ws2 + _c); \
        u3 = *(const uint4*)(wB + ws3 + _c); \
    } else { \
        wa0 = *(const float4*)(wF + ws0 + _c); wb0 = *(const float4*)(wF + ws0 + _c + 4); \
        wa1 = *(const float4*)(wF + ws1 + _c); wb1 = *(const float4*)(wF + ws1 + _c + 4); \
        wa2 = *(const float4*)(wF + ws2 + _c); wb2 = *(const float4*)(wF + ws2 + _c + 4); \
        wa3 = *(const float4*)(wF + ws3 + _c); wb3 = *(const float4*)(wF + ws3 + _c + 4); \
    } \
} while(0)

// scatter 8 shorts (d0..d0+3 x t0..t1) of one rr into Wt: [dd 4][oo 64][t*16+c pad40]
#define STW_RR(Wt_, uu_, fa_, fb_, oo_) do { \
    unsigned short w0_,w1_,w2_,w3_,w4_,w5_,w6_,w7_; \
    if (WBF){ const unsigned short* _pu = (const unsigned short*)&(uu_); \
        w0_=_pu[0]; w1_=_pu[1]; w2_=_pu[2]; w3_=_pu[3]; w4_=_pu[4]; w5_=_pu[5]; w6_=_pu[6]; w7_=_pu[7]; \
    } else { \
        w0_=f2bf((fa_).x); w1_=f2bf((fa_).y); w2_=f2bf((fa_).z); w3_=f2bf((fa_).w); \
        w4_=f2bf((fb_).x); w5_=f2bf((fb_).y); w6_=f2bf((fb_).z); w7_=f2bf((fb_).w); \
    } \
    (Wt_)[((0*64) + (oo_))*40 +  0 + cl] = w0_;  /* dd0 t0 */ \
    (Wt_)[((0*64) + (oo_))*40 + 16 + cl] = w1_;  /* dd0 t1 */ \
    (Wt_)[((1*64) + (oo_))*40 +  0 + cl] = w2_; \
    (Wt_)[((1*64) + (oo_))*40 + 16 + cl] = w3_; \
    (Wt_)[((2*64) + (oo_))*40 +  0 + cl] = w4_; \
    (Wt_)[((2*64) + (oo_))*40 + 16 + cl] = w5_; \
    (Wt_)[((3*64) + (oo_))*40 +  0 + cl] = w6_; \
    (Wt_)[((3*64) + (oo_))*40 + 16 + cl] = w7_; \
} while(0)

#define STOREW(Wt_) do { \
    STW_RR(Wt_, u0, wa0, wb0, ooB      ); \
    STW_RR(Wt_, u1, wa1, wb1, ooB + 16 ); \
    STW_RR(Wt_, u2, wa2, wb2, ooB + 32 ); \
    STW_RR(Wt_, u3, wa3, wb3, ooB + 48 ); \
} while(0)

    // prologue: fill buffer 0, first A frags
    LOADW(0);
    LOADA4(a0, a1, a2, a3, 0);
    STOREW(Wt0);

    for (int s = 0; s < TS; ++s){
        __syncthreads();                       // Wt[s&1] writes visible; prior reads done
        if (s + 1 < TS){
            LOADA4(n0, n1, n2, n3, s + 1);     // prefetch next A
            LOADW(s + 1);                      // prefetch next W (in flight over compute)
        }
        const unsigned short* Wr = (s & 1) ? Wt1 : Wt0;
        shortx8 br0 = *(const shortx8*)(Wr + (wv_*64 +  0 + mr)*40 + g*8);
        shortx8 br1 = *(const shortx8*)(Wr + (wv_*64 + 16 + mr)*40 + g*8);
        shortx8 br2 = *(const shortx8*)(Wr + (wv_*64 + 32 + mr)*40 + g*8);
        shortx8 br3 = *(const shortx8*)(Wr + (wv_*64 + 48 + mr)*40 + g*8);
#define MFMA_ROW(m_, ar_) \
        acc[m_][0] = __builtin_amdgcn_mfma_f32_16x16x32_bf16(ar_, br0, acc[m_][0], 0,0,0); \
        acc[m_][1] = __builtin_amdgcn_mfma_f32_16x16x32_bf16(ar_, br1, acc[m_][1], 0,0,0); \
        acc[m_][2] = __builtin_amdgcn_mfma_f32_16x16x32_bf16(ar_, br2, acc[m_][2], 0,0,0); \
        acc[m_][3] = __builtin_amdgcn_mfma_f32_16x16x32_bf16(ar_, br3, acc[m_][3], 0,0,0);
        MFMA_ROW(0, a0)
        MFMA_ROW(1, a1)
        MFMA_ROW(2, a2)
        MFMA_ROW(3, a3)
#undef MFMA_ROW
        if (s + 1 < TS){
            STOREW((s & 1) ? Wt0 : Wt1);
            a0 = n0; a1 = n1; a2 = n2; a3 = n3;
        }
    }
#undef LOADA4
#undef LOADW
#undef STW_RR
#undef STOREW

    // ---- epilogue: D row=g*4+r -> b (relative), col=mr -> o
    #pragma unroll
    for (int m = 0; m < 4; ++m)
        #pragma unroll
        for (int nb = 0; nb < 4; ++nb)
            #pragma unroll
            for (int r = 0; r < 4; ++r){
                const int bb = b0 + m*16 + g*4 + r;
                const int oc = o0 + nb*16 + mr;
                if (ATOMIC)
                    unsafeAtomicAdd((float*)out + (dme*128 + bb)*256 + oc, acc[m][nb][r]);
                else
                    ((unsigned short*)out)[dme*32768 + bb*256 + oc] =
                        f2bf(fmaxf(acc[m][nb][r], 0.f) * 0.0625f);
            }
}

template<bool ATOMIC>
__global__ __launch_bounds__(256,2) void layer_main_k(const int* __restrict__ flag,
        const unsigned short* __restrict__ Ain, const void* __restrict__ wv,
        void* __restrict__ out, int dl, int ks){
    // Wt only: 2 x 20 KB = 40 KB -> 2 blocks/CU co-resident.
    __shared__ unsigned short Wt[2][4*64*40];
    if (*flag) layer_main_impl<true,  ATOMIC>(Ain, wv, out, dl, ks, Wt[0], Wt[1]);
    else       layer_main_impl<false, ATOMIC>(Ain, wv, out, dl, ks, Wt[0], Wt[1]);
}

// ---------------------------------------------------------------------------
// Tail layers (dl<=2): direct gather (weights ~1MB, L2-resident), atomic fp32 out.
// k-order c-minor: k = c*2 + t.
template<bool WBF>
__device__ __forceinline__ void tail_impl(const unsigned short* __restrict__ Ain,
        const void* __restrict__ wv, float* __restrict__ outS, int dl, int ksplit){
    int id = blockIdx.x;
    int d = id % dl; int t2 = id / dl;
    int ob = t2 & 3; int ksid = t2 >> 2;
    const int KSEG = 512 / ksplit;
    const int k0s = ksid * KSEG;
    const int lane = threadIdx.x & 63, wv2 = threadIdx.x >> 6;
    const int mr = lane & 15, kg = lane >> 4;
    const float* wF = (const float*)wv;
    const unsigned short* wB = (const unsigned short*)wv;
    floatx4 acc[2][4];
    #pragma unroll
    for (int mi = 0; mi < 2; ++mi)
        #pragma unroll
        for (int ni = 0; ni < 4; ++ni) acc[mi][ni] = (floatx4){0.f,0.f,0.f,0.f};
    for (int k0 = k0s; k0 < k0s + KSEG; k0 += 32){
        int c0 = (k0 >> 1) + kg*4;
        shortx8 af[2];
        #pragma unroll
        for (int mi = 0; mi < 2; ++mi){
            int b = wv2*32 + mi*16 + mr;
            #pragma unroll
            for (int cc = 0; cc < 4; ++cc){
                af[mi][2*cc]   = (short)Ain[(2*d)*32768   + b*256 + c0 + cc];
                af[mi][2*cc+1] = (short)Ain[(2*d+1)*32768 + b*256 + c0 + cc];
            }
        }
        shortx8 bf_[4];
        #pragma unroll
        for (int ni = 0; ni < 4; ++ni){
            int o = ob*64 + ni*16 + mr;
            int base = ((o*256 + c0)*dl + d)*2;
            #pragma unroll
            for (int cc = 0; cc < 4; ++cc){
                if (WBF){
                    unsigned int u = *(const unsigned int*)(wB + base);
                    bf_[ni][2*cc]   = (short)(u & 0xFFFFu);
                    bf_[ni][2*cc+1] = (short)(u >> 16);
                } else {
                    bf_[ni][2*cc]   = (short)f2bf(wF[base]);
                    bf_[ni][2*cc+1] = (short)f2bf(wF[base+1]);
                }
                base += 2*dl;
            }
        }
        #pragma unroll
        for (int mi = 0; mi < 2; ++mi)
            #pragma unroll
            for (int ni = 0; ni < 4; ++ni)
                acc[mi][ni] = __builtin_amdgcn_mfma_f32_16x16x32_bf16(af[mi], bf_[ni], acc[mi][ni], 0,0,0);
    }
    #pragma unroll
    for (int mi = 0; mi < 2; ++mi)
        #pragma unroll
        for (int ni = 0; ni < 4; ++ni)
            #pragma unroll
            for (int r = 0; r < 4; ++r){
                int b = wv2*32 + mi*16 + kg*4 + r;
                int o = ob*64 + ni*16 + mr;
                unsafeAtomicAdd(outS + (d*128 + b)*256 + o, acc[mi][ni][r]);
            }
}
__global__ __launch_bounds__(256) void tail_k(const int* __restrict__ flag,
        const unsigned short* __restrict__ Ain, const void* __restrict__ wv,
        float* __restrict__ outS, int dl, int ksplit){
    if (*flag) tail_impl<true >(Ain, wv, outS, dl, ksplit);
    else       tail_impl<false>(Ain, wv, outS, dl, ksplit);
}

// ---------------------------------------------------------------------------
// Finalize: A_{l+1}[i] = bf16(relu(S_l[i]) / 16)   (identity index map)
__global__ __launch_bounds__(256) void fin_kernel(const float* __restrict__ S,
        unsigned short* __restrict__ A, int n){
    int i = (blockIdx.x*256 + threadIdx.x)*4;
    if (i + 3 < n){
        float4 v = *(const float4*)(S + i);
        unsigned short r0 = f2bf(fmaxf(v.x,0.f)*0.0625f);
        unsigned short r1 = f2bf(fmaxf(v.y,0.f)*0.0625f);
        unsigned short r2 = f2bf(fmaxf(v.z,0.f)*0.0625f);
        unsigned short r3 = f2bf(fmaxf(v.w,0.f)*0.0625f);
        unsigned int lo = (unsigned int)r0 | ((unsigned int)r1 << 16);
        unsigned int hi = (unsigned int)r2 | ((unsigned int)r3 << 16);
        uint2 u; u.x = lo; u.y = hi;
        *(uint2*)(A + i) = u;
    }
}

// ---------------------------------------------------------------------------
// Epilogue (verified): out[b,o] = (sum_h relu(S9[b,h])/16 * beta[h,o]) / 256
template<bool BF>
__device__ __forceinline__ void epi_impl(const float* __restrict__ S9, const void* __restrict__ beta,
                                         void* __restrict__ out){
    int b = blockIdx.x;
    int lane = threadIdx.x;
    float accv[10];
    #pragma unroll
    for (int o = 0; o < 10; ++o) accv[o] = 0.f;
    for (int h = lane; h < 256; h += 64){
        float y = fmaxf(S9[b*256 + h], 0.f) * 0.0625f;
        #pragma unroll
        for (int o = 0; o < 10; ++o){
            float be = BF ? bf2f(((const unsigned short*)beta)[h*10 + o])
                          : ((const float*)beta)[h*10 + o];
            accv[o] += y * be;
        }
    }
    #pragma unroll
    for (int off = 32; off > 0; off >>= 1){
        #pragma unroll
        for (int o = 0; o < 10; ++o)
            accv[o] += __shfl_down(accv[o], off, 64);
    }
    if (lane == 0){
        #pragma unroll
        for (int o = 0; o < 10; ++o){
            float v = accv[o] * (1.f/256.f);
            if (BF) ((unsigned short*)out)[b*10 + o] = f2bf(v);
            else    ((float*)out)[b*10 + o] = v;
        }
    }
}
__global__ void epi_kernel(const int* __restrict__ flag, const float* __restrict__ S9,
                           const void* __restrict__ beta, void* __restrict__ out){
    if (*flag) epi_impl<true>(S9, beta, out);
    else       epi_impl<false>(S9, beta, out);
}

// ---------------------------------------------------------------------------
extern "C" void kernel_launch(void* const* d_in, const int* in_sizes, int n_in,
                              void* d_out, int out_size, void* d_ws, size_t ws_size,
                              hipStream_t stream) {
    (void)in_sizes; (void)n_in; (void)out_size; (void)ws_size;
    char* wsb = (char*)d_ws;
    int* flag = (int*)wsb;
    // region1: A1, later overwritten by S2..S9 (fp32)
    unsigned short* A1 = (unsigned short*)(wsb + 512);
    float* S2 = (float*)(wsb + 512);
    float* S3 = S2 + 4194304;
    float* S4 = S3 + 2097152;
    float* S5 = S4 + 1048576;
    float* S6 = S5 + 524288;
    float* S7 = S6 + 262144;
    float* S8 = S7 + 131072;
    float* S9 = S8 + 65536;
    // region2: A2, later overlaid by A3..A9
    unsigned short* A2 = (unsigned short*)(wsb + 512 + 33554432);
    unsigned short* A3 = A2;
    unsigned short* A4 = A3 + 4194304;
    unsigned short* A5 = A4 + 2097152;
    unsigned short* A6 = A5 + 1048576;
    unsigned short* A7 = A6 + 524288;
    unsigned short* A8 = A7 + 262144;
    unsigned short* A9 = A8 + 131072;

    probe_kernel<<<1, 256, 0, stream>>>((const unsigned int*)d_in[0], flag);
    l0_kernel<<<512, 256, 0, stream>>>(flag, d_in[0], d_in[1], A1);
    // main-layer grids: nd * 4(ng) * 2(mh) * ks
    // l1: reads A1 (region1), writes bf16 A2 (region2) -- ks=1, non-atomic
    layer_main_k<false><<<512, 256, 0, stream>>>(flag, A1, d_in[2], A2, 256, 1);
    // A1 now dead: zero S region (covers S2..S9) for atomic layers
    hipMemsetAsync(S2, 0, 33423360, stream);
    layer_main_k<true ><<<512, 256, 0, stream>>>(flag, A2, d_in[3], S2, 128, 2);
    fin_kernel<<<4096, 256, 0, stream>>>(S2, A3, 4194304);
    layer_main_k<true ><<<512, 256, 0, stream>>>(flag, A3, d_in[4], S3, 64, 4);
    fin_kernel<<<2048, 256, 0, stream>>>(S3, A4, 2097152);
    layer_main_k<true ><<<512, 256, 0, stream>>>(flag, A4, d_in[5], S4, 32, 8);
    fin_kernel<<<1024, 256, 0, stream>>>(S4, A5, 1048576);
    layer_main_k<true ><<<512, 256, 0, stream>>>(flag, A5, d_in[6], S5, 16, 16);
    fin_kernel<<<512, 256, 0, stream>>>(S5, A6, 524288);
    layer_main_k<true ><<<256, 256, 0, stream>>>(flag, A6, d_in[7], S6, 8, 16);
    fin_kernel<<<256, 256, 0, stream>>>(S6, A7, 262144);
    layer_main_k<true ><<<128, 256, 0, stream>>>(flag, A7, d_in[8], S7, 4, 16);
    fin_kernel<<<128, 256, 0, stream>>>(S7, A8, 131072);
    tail_k<<<128, 256, 0, stream>>>(flag, A8, d_in[9], S8, 2, 16);
    fin_kernel<<<64, 256, 0, stream>>>(S8, A9, 65536);
    tail_k<<<64, 256, 0, stream>>>(flag, A9, d_in[10], S9, 1, 16);
    epi_kernel<<<128, 64, 0, stream>>>(flag, S9, d_in[11], d_out);
}

// Round 5
// 586.821 us; speedup vs baseline: 1.0984x; 1.0825x over previous
//
#include <hip/hip_runtime.h>
#include <hip/hip_bf16.h>
#include <stdint.h>

// R7: kill the split-K atomic storm. Main-layer inner loop is BYTE-IDENTICAL
// to R6 (l1 = A/B control). Change: ATOMIC layers now store disjoint partials
// P[ksid][p][b][o] (plain coalesced stores, no RMW) into the 33.55-MB region-1
// scratch; fin sums the ks planes (+relu+bf16). Tails likewise. Memset removed
// (every partial element written exactly once).
// Why: l2..l7 + tails issued ~52M device-scope 4-B atomicAdds per iteration
// (8.4M per layer by construction) — invisible in top-5 counters but consistent
// with the wall being pinned at ~635us across R2/R3/R6 while l1 varied ±30us.
// Scratch fit (region1 = 33554432 B = 8388608 floats):
//   l2: 4.19M x ks2 = 8.39M  l3: 2.10M x 4  l4: 1.05M x 8  l5: 524K x 16
//   l6: 262K x 16 = 4.2M     l7: 131K x 16  l8: 65K x 16   l9: 32K x 16  (all <= 8.39M)

typedef __attribute__((ext_vector_type(4))) float floatx4;
typedef __attribute__((ext_vector_type(8))) short shortx8;

__device__ __forceinline__ float bf2f(unsigned short u){
    union { unsigned int u; float f; } c; c.u = ((unsigned int)u) << 16; return c.f;
}
__device__ __forceinline__ unsigned short f2bf(float f){
    union { float f; unsigned int u; } c; c.f = f;
    unsigned int x = c.u;
    x += 0x7FFFu + ((x >> 16) & 1u);
    return (unsigned short)(x >> 16);
}

// ---------------------------------------------------------------------------
// dtype probe (unchanged, verified working)
__global__ void probe_kernel(const unsigned int* __restrict__ x, int* __restrict__ flag){
    __shared__ int cnt[256];
    int tid = threadIdx.x;
    unsigned short lo = (unsigned short)(x[tid] & 0xFFFFu);
    int e = (lo >> 7) & 0xFF;
    cnt[tid] = (e >= 90 && e <= 143) ? 1 : 0;
    __syncthreads();
    for (int s = 128; s > 0; s >>= 1){
        if (tid < s) cnt[tid] += cnt[tid + s];
        __syncthreads();
    }
    if (tid == 0) *flag = (cnt[0] > 160) ? 1 : 0;
}

// ---------------------------------------------------------------------------
// Layer 0: A1[p=d][b][o] = relu(sum_{c,t} x[b,c,2d+t]*w0[o,c,d,t]) * (1/sqrt(3))
__global__ __launch_bounds__(256) void l0_kernel(const int* __restrict__ flag,
        const void* __restrict__ xv, const void* __restrict__ wv,
        unsigned short* __restrict__ A1){
    __shared__ float Xs[128*6];
    const int d = blockIdx.x;
    const int tid = threadIdx.x;
    const bool BF = (*flag != 0);
    for (int i = tid; i < 384; i += 256){
        int b = i / 3, c = i - b*3;
        if (BF){
            unsigned int u = *(const unsigned int*)((const unsigned short*)xv + (b*3+c)*1024 + 2*d);
            Xs[b*6 + c*2]     = bf2f((unsigned short)(u & 0xFFFFu));
            Xs[b*6 + c*2 + 1] = bf2f((unsigned short)(u >> 16));
        } else {
            const float* xf = (const float*)xv + (b*3+c)*1024 + 2*d;
            Xs[b*6 + c*2] = xf[0]; Xs[b*6 + c*2 + 1] = xf[1];
        }
    }
    __syncthreads();
    const int o = tid;
    float wr[6];
    #pragma unroll
    for (int c = 0; c < 3; ++c){
        if (BF){
            unsigned int u = *(const unsigned int*)((const unsigned short*)wv + ((o*3+c)*512 + d)*2);
            wr[c*2]   = bf2f((unsigned short)(u & 0xFFFFu));
            wr[c*2+1] = bf2f((unsigned short)(u >> 16));
        } else {
            const float* wf = (const float*)wv + ((o*3+c)*512 + d)*2;
            wr[c*2] = wf[0]; wr[c*2+1] = wf[1];
        }
    }
    const float s3 = 0.57735026918962576f;
    for (int b = 0; b < 128; ++b){
        float s = 0.f;
        #pragma unroll
        for (int j = 0; j < 6; ++j) s += Xs[b*6 + j] * wr[j];
        A1[d*32768 + b*256 + o] = f2bf(fmaxf(s, 0.f) * s3);
    }
}

// ---------------------------------------------------------------------------
// Main layer kernel. Logical block = (dg: d-group of 4, ng: o-group of 64,
// mh: batch half of 64, ksid: k-slice). Wave <-> d. A read direct from global
// (wave-private rows); W staged through double-buffered LDS (transpose).
// k-order within a K=32 MFMA step: k = t*16 + c_local (t = g>>1, c = (g&1)*8+j).
// PARTIAL=true: store fp32 partial into out + ksid*(dl<<15) (disjoint, no atomics).
// PARTIAL=false: fused relu*(1/16) bf16 store (l1 only, ks==1).
template<bool WBF, bool PARTIAL>
__device__ __forceinline__ void layer_main_impl(const unsigned short* __restrict__ Ain,
        const void* __restrict__ wv, void* __restrict__ out, int dl, int ks,
        unsigned short* __restrict__ Wt0, unsigned short* __restrict__ Wt1){
    const int tid  = threadIdx.x;
    const int lane = tid & 63, wv_ = tid >> 6;
    const int g = lane >> 4, mr = lane & 15;
    const int nd = dl >> 2;

    // XCD co-location: 16 blocks {dg&1 x ng x mh} sharing W sectors / A rows
    // placed == mod 8 -> same XCD. Bijective when nd>=2 and G%128==0.
    int dg, ng, mh, ksid;
    {
        const int bi = blockIdx.x;
        const int G  = gridDim.x;
        if (nd >= 2 && (G & 127) == 0){
            const int x = bi & 7, j = (bi >> 3) & 15, gg = bi >> 7;
            const int pid = gg*8 + x;          // [0, nd2*ks)
            const int nd2 = nd >> 1;
            dg   = (pid % nd2)*2 + (j & 1);
            ng   = (j >> 1) & 3;
            mh   = j >> 3;
            ksid = pid / nd2;
        } else {
            dg = bi % nd; const int r = bi / nd;
            ng = r & 3; mh = (r >> 2) & 1; ksid = r >> 3;
        }
    }
    const int TS = 16 / ks;
    const int d0 = dg << 2;
    const int o0 = ng << 6;
    const int b0 = mh << 6;
    const int dme = d0 + wv_;
    const float* wF = (const float*)wv;
    const unsigned short* wB = (const unsigned short*)wv;

    // ---- W staging addressing (per-thread): cl = c_local, oo_rr = rr*16 + tid>>4
    const int cl  = tid & 15;
    const int ooB = tid >> 4;                  // oo for rr=0 (local o in [0,64))
    const int ws0 = (((o0 + ooB      )*256 + cl)*dl + d0)*2;
    const int ws1 = (((o0 + ooB + 16 )*256 + cl)*dl + d0)*2;
    const int ws2 = (((o0 + ooB + 32 )*256 + cl)*dl + d0)*2;
    const int ws3 = (((o0 + ooB + 48 )*256 + cl)*dl + d0)*2;
    const int wcstep = 32*dl;                  // element delta for c0 += 16

    // ---- A direct-load base: p = 2*dme + (g>>1), b = b0 + m*16 + mr,
    //      c = c0 + (g&1)*8 + j   (matches k = t*16 + c_local with t = g>>1)
    const unsigned short* Ab = Ain + (2*dme + (g>>1))*32768 + (b0 + mr)*256 + (g&1)*8;
    const int c_base = ksid*TS;                // in 16-c units

    floatx4 acc[4][4];
    #pragma unroll
    for (int m = 0; m < 4; ++m)
        #pragma unroll
        for (int nb = 0; nb < 4; ++nb)
            acc[m][nb] = (floatx4){0.f,0.f,0.f,0.f};

    // ---- named prefetch registers (NO arrays -> no PromoteAlloca)
    shortx8 a0, a1, a2, a3;        // current A frags
    shortx8 n0, n1, n2, n3;        // next A frags
    uint4  u0, u1, u2, u3;         // W stage, bf16 path
    float4 wa0, wa1, wa2, wa3;     // W stage, fp32 path (lo half)
    float4 wb0, wb1, wb2, wb3;     //                    (hi half)

#define LOADA4(d0_,d1_,d2_,d3_,s_) do { \
    const unsigned short* _p = Ab + ((c_base + (s_)) << 4); \
    d0_ = *(const shortx8*)(_p);          \
    d1_ = *(const shortx8*)(_p + 4096);   \
    d2_ = *(const shortx8*)(_p + 8192);   \
    d3_ = *(const shortx8*)(_p + 12288);  \
} while(0)

#define LOADW(s_) do { \
    const int _c = (c_base + (s_)) * wcstep; \
    if (WBF){ \
        u0 = *(const uint4*)(wB + ws0 + _c); \
        u1 = *(const uint4*)(wB + ws1 + _c); \
        u2 = *(const uint4*)(wB + ws2 + _c); \
        u3 = *(const uint4*)(wB + ws3 + _c); \
    } else { \
        wa0 = *(const float4*)(wF + ws0 + _c); wb0 = *(const float4*)(wF + ws0 + _c + 4); \
        wa1 = *(const float4*)(wF + ws1 + _c); wb1 = *(const float4*)(wF + ws1 + _c + 4); \
        wa2 = *(const float4*)(wF + ws2 + _c); wb2 = *(const float4*)(wF + ws2 + _c + 4); \
        wa3 = *(const float4*)(wF + ws3 + _c); wb3 = *(const float4*)(wF + ws3 + _c + 4); \
    } \
} while(0)

// scatter 8 shorts (d0..d0+3 x t0..t1) of one rr into Wt: [dd 4][oo 64][t*16+c pad40]
#define STW_RR(Wt_, uu_, fa_, fb_, oo_) do { \
    unsigned short w0_,w1_,w2_,w3_,w4_,w5_,w6_,w7_; \
    if (WBF){ const unsigned short* _pu = (const unsigned short*)&(uu_); \
        w0_=_pu[0]; w1_=_pu[1]; w2_=_pu[2]; w3_=_pu[3]; w4_=_pu[4]; w5_=_pu[5]; w6_=_pu[6]; w7_=_pu[7]; \
    } else { \
        w0_=f2bf((fa_).x); w1_=f2bf((fa_).y); w2_=f2bf((fa_).z); w3_=f2bf((fa_).w); \
        w4_=f2bf((fb_).x); w5_=f2bf((fb_).y); w6_=f2bf((fb_).z); w7_=f2bf((fb_).w); \
    } \
    (Wt_)[((0*64) + (oo_))*40 +  0 + cl] = w0_;  /* dd0 t0 */ \
    (Wt_)[((0*64) + (oo_))*40 + 16 + cl] = w1_;  /* dd0 t1 */ \
    (Wt_)[((1*64) + (oo_))*40 +  0 + cl] = w2_; \
    (Wt_)[((1*64) + (oo_))*40 + 16 + cl] = w3_; \
    (Wt_)[((2*64) + (oo_))*40 +  0 + cl] = w4_; \
    (Wt_)[((2*64) + (oo_))*40 + 16 + cl] = w5_; \
    (Wt_)[((3*64) + (oo_))*40 +  0 + cl] = w6_; \
    (Wt_)[((3*64) + (oo_))*40 + 16 + cl] = w7_; \
} while(0)

#define STOREW(Wt_) do { \
    STW_RR(Wt_, u0, wa0, wb0, ooB      ); \
    STW_RR(Wt_, u1, wa1, wb1, ooB + 16 ); \
    STW_RR(Wt_, u2, wa2, wb2, ooB + 32 ); \
    STW_RR(Wt_, u3, wa3, wb3, ooB + 48 ); \
} while(0)

    // prologue: fill buffer 0, first A frags
    LOADW(0);
    LOADA4(a0, a1, a2, a3, 0);
    STOREW(Wt0);

    for (int s = 0; s < TS; ++s){
        __syncthreads();                       // Wt[s&1] writes visible; prior reads done
        if (s + 1 < TS){
            LOADA4(n0, n1, n2, n3, s + 1);     // prefetch next A
            LOADW(s + 1);                      // prefetch next W (in flight over compute)
        }
        const unsigned short* Wr = (s & 1) ? Wt1 : Wt0;
        shortx8 br0 = *(const shortx8*)(Wr + (wv_*64 +  0 + mr)*40 + g*8);
        shortx8 br1 = *(const shortx8*)(Wr + (wv_*64 + 16 + mr)*40 + g*8);
        shortx8 br2 = *(const shortx8*)(Wr + (wv_*64 + 32 + mr)*40 + g*8);
        shortx8 br3 = *(const shortx8*)(Wr + (wv_*64 + 48 + mr)*40 + g*8);
#define MFMA_ROW(m_, ar_) \
        acc[m_][0] = __builtin_amdgcn_mfma_f32_16x16x32_bf16(ar_, br0, acc[m_][0], 0,0,0); \
        acc[m_][1] = __builtin_amdgcn_mfma_f32_16x16x32_bf16(ar_, br1, acc[m_][1], 0,0,0); \
        acc[m_][2] = __builtin_amdgcn_mfma_f32_16x16x32_bf16(ar_, br2, acc[m_][2], 0,0,0); \
        acc[m_][3] = __builtin_amdgcn_mfma_f32_16x16x32_bf16(ar_, br3, acc[m_][3], 0,0,0);
        MFMA_ROW(0, a0)
        MFMA_ROW(1, a1)
        MFMA_ROW(2, a2)
        MFMA_ROW(3, a3)
#undef MFMA_ROW
        if (s + 1 < TS){
            STOREW((s & 1) ? Wt0 : Wt1);
            a0 = n0; a1 = n1; a2 = n2; a3 = n3;
        }
    }
#undef LOADA4
#undef LOADW
#undef STW_RR
#undef STOREW

    // ---- epilogue: D row=g*4+r -> b (relative), col=mr -> o
    // PARTIAL: plain disjoint store into the ksid plane (no atomics).
    const size_t pofs = PARTIAL ? ((size_t)ksid * ((size_t)dl << 15)) : 0;
    #pragma unroll
    for (int m = 0; m < 4; ++m)
        #pragma unroll
        for (int nb = 0; nb < 4; ++nb)
            #pragma unroll
            for (int r = 0; r < 4; ++r){
                const int bb = b0 + m*16 + g*4 + r;
                const int oc = o0 + nb*16 + mr;
                if (PARTIAL)
                    ((float*)out)[pofs + (size_t)(dme*128 + bb)*256 + oc] = acc[m][nb][r];
                else
                    ((unsigned short*)out)[dme*32768 + bb*256 + oc] =
                        f2bf(fmaxf(acc[m][nb][r], 0.f) * 0.0625f);
            }
}

template<bool PARTIAL>
__global__ __launch_bounds__(256,2) void layer_main_k(const int* __restrict__ flag,
        const unsigned short* __restrict__ Ain, const void* __restrict__ wv,
        void* __restrict__ out, int dl, int ks){
    // Wt only: 2 x 20 KB = 40 KB -> 2 blocks/CU co-resident.
    __shared__ unsigned short Wt[2][4*64*40];
    if (*flag) layer_main_impl<true,  PARTIAL>(Ain, wv, out, dl, ks, Wt[0], Wt[1]);
    else       layer_main_impl<false, PARTIAL>(Ain, wv, out, dl, ks, Wt[0], Wt[1]);
}

// ---------------------------------------------------------------------------
// Tail layers (dl<=2): direct gather (weights ~1MB, L2-resident).
// Now writes disjoint fp32 partials P[ksid] (no atomics). k-order c-minor.
template<bool WBF>
__device__ __forceinline__ void tail_impl(const unsigned short* __restrict__ Ain,
        const void* __restrict__ wv, float* __restrict__ outP, int dl, int ksplit){
    int id = blockIdx.x;
    int d = id % dl; int t2 = id / dl;
    int ob = t2 & 3; int ksid = t2 >> 2;
    const int KSEG = 512 / ksplit;
    const int k0s = ksid * KSEG;
    const int lane = threadIdx.x & 63, wv2 = threadIdx.x >> 6;
    const int mr = lane & 15, kg = lane >> 4;
    const float* wF = (const float*)wv;
    const unsigned short* wB = (const unsigned short*)wv;
    floatx4 acc[2][4];
    #pragma unroll
    for (int mi = 0; mi < 2; ++mi)
        #pragma unroll
        for (int ni = 0; ni < 4; ++ni) acc[mi][ni] = (floatx4){0.f,0.f,0.f,0.f};
    for (int k0 = k0s; k0 < k0s + KSEG; k0 += 32){
        int c0 = (k0 >> 1) + kg*4;
        shortx8 af[2];
        #pragma unroll
        for (int mi = 0; mi < 2; ++mi){
            int b = wv2*32 + mi*16 + mr;
            #pragma unroll
            for (int cc = 0; cc < 4; ++cc){
                af[mi][2*cc]   = (short)Ain[(2*d)*32768   + b*256 + c0 + cc];
                af[mi][2*cc+1] = (short)Ain[(2*d+1)*32768 + b*256 + c0 + cc];
            }
        }
        shortx8 bf_[4];
        #pragma unroll
        for (int ni = 0; ni < 4; ++ni){
            int o = ob*64 + ni*16 + mr;
            int base = ((o*256 + c0)*dl + d)*2;
            #pragma unroll
            for (int cc = 0; cc < 4; ++cc){
                if (WBF){
                    unsigned int u = *(const unsigned int*)(wB + base);
                    bf_[ni][2*cc]   = (short)(u & 0xFFFFu);
                    bf_[ni][2*cc+1] = (short)(u >> 16);
                } else {
                    bf_[ni][2*cc]   = (short)f2bf(wF[base]);
                    bf_[ni][2*cc+1] = (short)f2bf(wF[base+1]);
                }
                base += 2*dl;
            }
        }
        #pragma unroll
        for (int mi = 0; mi < 2; ++mi)
            #pragma unroll
            for (int ni = 0; ni < 4; ++ni)
                acc[mi][ni] = __builtin_amdgcn_mfma_f32_16x16x32_bf16(af[mi], bf_[ni], acc[mi][ni], 0,0,0);
    }
    const size_t pofs = (size_t)ksid * ((size_t)dl << 15);
    #pragma unroll
    for (int mi = 0; mi < 2; ++mi)
        #pragma unroll
        for (int ni = 0; ni < 4; ++ni)
            #pragma unroll
            for (int r = 0; r < 4; ++r){
                int b = wv2*32 + mi*16 + kg*4 + r;
                int o = ob*64 + ni*16 + mr;
                outP[pofs + (size_t)(d*128 + b)*256 + o] = acc[mi][ni][r];
            }
}
__global__ __launch_bounds__(256) void tail_k(const int* __restrict__ flag,
        const unsigned short* __restrict__ Ain, const void* __restrict__ wv,
        float* __restrict__ outP, int dl, int ksplit){
    if (*flag) tail_impl<true >(Ain, wv, outP, dl, ksplit);
    else       tail_impl<false>(Ain, wv, outP, dl, ksplit);
}

// ---------------------------------------------------------------------------
// Finalize: A_{l+1}[i] = bf16(relu(sum_{k<ks} P[k][i]) / 16)
__global__ __launch_bounds__(256) void fin_kernel(const float* __restrict__ P,
        unsigned short* __restrict__ A, int n, int ks){
    int i = (blockIdx.x*256 + threadIdx.x)*4;
    if (i + 3 < n){
        float4 v = *(const float4*)(P + i);
        for (int k = 1; k < ks; ++k){
            float4 w = *(const float4*)(P + (size_t)k*n + i);
            v.x += w.x; v.y += w.y; v.z += w.z; v.w += w.w;
        }
        unsigned short r0 = f2bf(fmaxf(v.x,0.f)*0.0625f);
        unsigned short r1 = f2bf(fmaxf(v.y,0.f)*0.0625f);
        unsigned short r2 = f2bf(fmaxf(v.z,0.f)*0.0625f);
        unsigned short r3 = f2bf(fmaxf(v.w,0.f)*0.0625f);
        unsigned int lo = (unsigned int)r0 | ((unsigned int)r1 << 16);
        unsigned int hi = (unsigned int)r2 | ((unsigned int)r3 << 16);
        uint2 u; u.x = lo; u.y = hi;
        *(uint2*)(A + i) = u;
    }
}

// ---------------------------------------------------------------------------
// Epilogue: out[b,o] = (sum_h relu(sum_k P9[k][b][h])/16 * beta[h,o]) / 256
template<bool BF>
__device__ __forceinline__ void epi_impl(const float* __restrict__ P9, const void* __restrict__ beta,
                                         void* __restrict__ out){
    int b = blockIdx.x;
    int lane = threadIdx.x;
    float accv[10];
    #pragma unroll
    for (int o = 0; o < 10; ++o) accv[o] = 0.f;
    for (int h = lane; h < 256; h += 64){
        float s = 0.f;
        #pragma unroll
        for (int k = 0; k < 16; ++k)
            s += P9[(size_t)k*32768 + b*256 + h];
        float y = fmaxf(s, 0.f) * 0.0625f;
        #pragma unroll
        for (int o = 0; o < 10; ++o){
            float be = BF ? bf2f(((const unsigned short*)beta)[h*10 + o])
                          : ((const float*)beta)[h*10 + o];
            accv[o] += y * be;
        }
    }
    #pragma unroll
    for (int off = 32; off > 0; off >>= 1){
        #pragma unroll
        for (int o = 0; o < 10; ++o)
            accv[o] += __shfl_down(accv[o], off, 64);
    }
    if (lane == 0){
        #pragma unroll
        for (int o = 0; o < 10; ++o){
            float v = accv[o] * (1.f/256.f);
            if (BF) ((unsigned short*)out)[b*10 + o] = f2bf(v);
            else    ((float*)out)[b*10 + o] = v;
        }
    }
}
__global__ void epi_kernel(const int* __restrict__ flag, const float* __restrict__ P9,
                           const void* __restrict__ beta, void* __restrict__ out){
    if (*flag) epi_impl<true>(P9, beta, out);
    else       epi_impl<false>(P9, beta, out);
}

// ---------------------------------------------------------------------------
extern "C" void kernel_launch(void* const* d_in, const int* in_sizes, int n_in,
                              void* d_out, int out_size, void* d_ws, size_t ws_size,
                              hipStream_t stream) {
    (void)in_sizes; (void)n_in; (void)out_size; (void)ws_size;
    char* wsb = (char*)d_ws;
    int* flag = (int*)wsb;
    // region1 (33.55 MB): A1 first, then per-layer partial scratch P (reused serially)
    unsigned short* A1 = (unsigned short*)(wsb + 512);
    float* P = (float*)(wsb + 512);
    // region2 (16.78 MB): A2, later overlaid by A3..A9
    unsigned short* A2 = (unsigned short*)(wsb + 512 + 33554432);
    unsigned short* A3 = A2;
    unsigned short* A4 = A3 + 4194304;
    unsigned short* A5 = A4 + 2097152;
    unsigned short* A6 = A5 + 1048576;
    unsigned short* A7 = A6 + 524288;
    unsigned short* A8 = A7 + 262144;
    unsigned short* A9 = A8 + 131072;

    probe_kernel<<<1, 256, 0, stream>>>((const unsigned int*)d_in[0], flag);
    l0_kernel<<<512, 256, 0, stream>>>(flag, d_in[0], d_in[1], A1);
    // main-layer grids: nd * 4(ng) * 2(mh) * ks
    // l1: reads A1 (region1), writes bf16 A2 (region2) -- ks=1, direct bf16
    layer_main_k<false><<<512, 256, 0, stream>>>(flag, A1, d_in[2], A2, 256, 1);
    // A1 now dead; region1 becomes partial scratch P. No memset needed:
    // each layer fully writes its ks x out partial planes before fin reads them.
    layer_main_k<true ><<<512, 256, 0, stream>>>(flag, A2, d_in[3], P, 128, 2);
    fin_kernel<<<4096, 256, 0, stream>>>(P, A3, 4194304, 2);
    layer_main_k<true ><<<512, 256, 0, stream>>>(flag, A3, d_in[4], P, 64, 4);
    fin_kernel<<<2048, 256, 0, stream>>>(P, A4, 2097152, 4);
    layer_main_k<true ><<<512, 256, 0, stream>>>(flag, A4, d_in[5], P, 32, 8);
    fin_kernel<<<1024, 256, 0, stream>>>(P, A5, 1048576, 8);
    layer_main_k<true ><<<512, 256, 0, stream>>>(flag, A5, d_in[6], P, 16, 16);
    fin_kernel<<<512, 256, 0, stream>>>(P, A6, 524288, 16);
    layer_main_k<true ><<<256, 256, 0, stream>>>(flag, A6, d_in[7], P, 8, 16);
    fin_kernel<<<256, 256, 0, stream>>>(P, A7, 262144, 16);
    layer_main_k<true ><<<128, 256, 0, stream>>>(flag, A7, d_in[8], P, 4, 16);
    fin_kernel<<<128, 256, 0, stream>>>(P, A8, 131072, 16);
    tail_k<<<128, 256, 0, stream>>>(flag, A8, d_in[9], P, 2, 16);
    fin_kernel<<<64, 256, 0, stream>>>(P, A9, 65536, 16);
    tail_k<<<64, 256, 0, stream>>>(flag, A9, d_in[10], P, 1, 16);
    epi_kernel<<<128, 64, 0, stream>>>(flag, P, d_in[11], d_out);
}

// Round 7
// 551.535 us; speedup vs baseline: 1.1686x; 1.0640x over previous
//
#include <hip/hip_runtime.h>
#include <hip/hip_bf16.h>
#include <stdint.h>

// R9 == R8 resubmit (round-6 bench died at broker/container level; same infra
// signature as rounds 1-2 which passed on identical resubmit at round 3.
// R8's new paths audited: tr_k bounds, layer_t_k swizzle bijectivity per grid,
// adaptive ws_size guard -> no OOB/hang constructible).
// R8: weight pre-transpose -> fully-coalesced layer reads.
// Evidence: l1 pinned at 117-150us across R2/R3/R6/R7 while FETCH (325->149MB),
// LDS conflicts (0.26->11->0.5M) and occupancy (9-17%) all swung -> bound by
// scattered 16-B W requests (16B-used-of-1KB-stride, 8.4M lines, channel-aliased).
// Fix: per layer, transpose W once (both sides coalesced via LDS tile) into
//   WT[s=c>>4][o][d][t*16+cl]  (32 shorts = 64B per (s,o,d), consecutive d adjacent)
// then the layer kernel B-frag is a direct 16-B load from a fully-used 64-B line:
// no LDS, no barriers (waves own disjoint d). b split in quarters -> 16 waves/CU.
// Launcher is ADAPTIVE on ws_size: transposed path per layer iff WT fits after the
// legacy 50.3-MB layout; else R7 path (current best) for that layer.

typedef __attribute__((ext_vector_type(4))) float floatx4;
typedef __attribute__((ext_vector_type(8))) short shortx8;

__device__ __forceinline__ float bf2f(unsigned short u){
    union { unsigned int u; float f; } c; c.u = ((unsigned int)u) << 16; return c.f;
}
__device__ __forceinline__ unsigned short f2bf(float f){
    union { float f; unsigned int u; } c; c.f = f;
    unsigned int x = c.u;
    x += 0x7FFFu + ((x >> 16) & 1u);
    return (unsigned short)(x >> 16);
}

// ---------------------------------------------------------------------------
// dtype probe (unchanged, verified)
__global__ void probe_kernel(const unsigned int* __restrict__ x, int* __restrict__ flag){
    __shared__ int cnt[256];
    int tid = threadIdx.x;
    unsigned short lo = (unsigned short)(x[tid] & 0xFFFFu);
    int e = (lo >> 7) & 0xFF;
    cnt[tid] = (e >= 90 && e <= 143) ? 1 : 0;
    __syncthreads();
    for (int s = 128; s > 0; s >>= 1){
        if (tid < s) cnt[tid] += cnt[tid + s];
        __syncthreads();
    }
    if (tid == 0) *flag = (cnt[0] > 160) ? 1 : 0;
}

// ---------------------------------------------------------------------------
// Layer 0 (unchanged, verified)
__global__ __launch_bounds__(256) void l0_kernel(const int* __restrict__ flag,
        const void* __restrict__ xv, const void* __restrict__ wv,
        unsigned short* __restrict__ A1){
    __shared__ float Xs[128*6];
    const int d = blockIdx.x;
    const int tid = threadIdx.x;
    const bool BF = (*flag != 0);
    for (int i = tid; i < 384; i += 256){
        int b = i / 3, c = i - b*3;
        if (BF){
            unsigned int u = *(const unsigned int*)((const unsigned short*)xv + (b*3+c)*1024 + 2*d);
            Xs[b*6 + c*2]     = bf2f((unsigned short)(u & 0xFFFFu));
            Xs[b*6 + c*2 + 1] = bf2f((unsigned short)(u >> 16));
        } else {
            const float* xf = (const float*)xv + (b*3+c)*1024 + 2*d;
            Xs[b*6 + c*2] = xf[0]; Xs[b*6 + c*2 + 1] = xf[1];
        }
    }
    __syncthreads();
    const int o = tid;
    float wr[6];
    #pragma unroll
    for (int c = 0; c < 3; ++c){
        if (BF){
            unsigned int u = *(const unsigned int*)((const unsigned short*)wv + ((o*3+c)*512 + d)*2);
            wr[c*2]   = bf2f((unsigned short)(u & 0xFFFFu));
            wr[c*2+1] = bf2f((unsigned short)(u >> 16));
        } else {
            const float* wf = (const float*)wv + ((o*3+c)*512 + d)*2;
            wr[c*2] = wf[0]; wr[c*2+1] = wf[1];
        }
    }
    const float s3 = 0.57735026918962576f;
    for (int b = 0; b < 128; ++b){
        float s = 0.f;
        #pragma unroll
        for (int j = 0; j < 6; ++j) s += Xs[b*6 + j] * wr[j];
        A1[d*32768 + b*256 + o] = f2bf(fmaxf(s, 0.f) * s3);
    }
}

// ---------------------------------------------------------------------------
// Weight transpose: W[o][c][d][t] (fp32 or bf16) -> WT[s][o][d][t*16+cl] bf16,
// s = c>>4, cl = c&15. Block = (o, s). Read coalesced (contiguous (d,t) runs),
// write coalesced (consecutive d -> contiguous 64-B runs). LDS tile in between.
template<bool WBF>
__device__ __forceinline__ void tr_impl(const void* __restrict__ src,
        unsigned short* __restrict__ dst, int dl, unsigned short* __restrict__ T){
    const int bi = blockIdx.x;
    const int o = bi >> 4, s = bi & 15;
    const int tid = threadIdx.x;
    const int PS = dl*2 + 8;                       // padded c-row stride (shorts)
    if (WBF){
        const unsigned short* W = (const unsigned short*)src;
        const int rl = dl >> 2;                    // 16-B granules per c-run
        for (int gs = tid; gs < 4*dl; gs += 256){
            int c = gs / rl, dq = gs - c*rl;
            uint4 v = *(const uint4*)(W + (size_t)(o*256 + s*16 + c)*dl*2 + dq*8);
            *(uint4*)(&T[c*PS + dq*8]) = v;
        }
    } else {
        const float* W = (const float*)src;
        const int rl = dl >> 1;                    // float4 granules per c-run
        for (int gs = tid; gs < 8*dl; gs += 256){
            int c = gs / rl, dq = gs - c*rl;
            float4 v = *(const float4*)(W + (size_t)(o*256 + s*16 + c)*dl*2 + dq*4);
            int b = c*PS + dq*4;
            T[b] = f2bf(v.x); T[b+1] = f2bf(v.y); T[b+2] = f2bf(v.z); T[b+3] = f2bf(v.w);
        }
    }
    __syncthreads();
    if (tid < dl){
        const int d2 = tid*2;
        unsigned short* O = dst + ((size_t)(s*256 + o)*dl + tid)*32;
#define PK(c0_,t_) ((unsigned int)T[(c0_)*PS + d2 + (t_)] | ((unsigned int)T[((c0_)+1)*PS + d2 + (t_)] << 16))
        uint4 q0 = {PK(0,0), PK(2,0), PK(4,0),  PK(6,0)};
        uint4 q1 = {PK(8,0), PK(10,0), PK(12,0), PK(14,0)};
        uint4 q2 = {PK(0,1), PK(2,1), PK(4,1),  PK(6,1)};
        uint4 q3 = {PK(8,1), PK(10,1), PK(12,1), PK(14,1)};
#undef PK
        *(uint4*)(O)      = q0;
        *(uint4*)(O + 8)  = q1;
        *(uint4*)(O + 16) = q2;
        *(uint4*)(O + 24) = q3;
    }
}
__global__ __launch_bounds__(256) void tr_k(const int* __restrict__ flag,
        const void* __restrict__ src, unsigned short* __restrict__ dst, int dl){
    __shared__ unsigned short T[16*520];           // hoisted: ONE copy (R3 lesson)
    if (*flag) tr_impl<true >(src, dst, dl, T);
    else       tr_impl<false>(src, dst, dl, T);
}

// ---------------------------------------------------------------------------
// Transposed-W main layer: no LDS, no barriers. Block = (dg 4d, ng 64o, bq 32b,
// ksid). Wave <-> d. B-frag: direct 16-B load from fully-used 64-B WT line.
// A-frag: direct 16-B load (R6 pattern, verified). k = t*16 + cl.
template<bool PARTIAL>
__global__ __launch_bounds__(256) void layer_t_k(const unsigned short* __restrict__ Ain,
        const unsigned short* __restrict__ WT, void* __restrict__ out, int dl, int ks){
    const int tid  = threadIdx.x;
    const int lane = tid & 63, wv_ = tid >> 6;
    const int g = lane >> 4, mr = lane & 15;
    const int nd = dl >> 2;
    // XCD co-location: 32 blocks {dg&1 x 4 ng x 4 bq} == mod 8 -> same XCD.
    int dg, ng, bq, ksid;
    {
        const int bi = blockIdx.x;
        const int G  = gridDim.x;
        if (nd >= 2 && (G & 255) == 0){
            const int x = bi & 7, j = (bi >> 3) & 31, gg = bi >> 8;
            const int pid = gg*8 + x;              // [0, nd2*ks)
            const int nd2 = nd >> 1;
            dg   = (pid % nd2)*2 + (j & 1);
            ng   = (j >> 1) & 3;
            bq   = (j >> 3) & 3;
            ksid = pid / nd2;
        } else {
            dg = bi % nd; const int r = bi / nd;
            ng = r & 3; bq = (r >> 2) & 3; ksid = r >> 4;
        }
    }
    const int TS = 16 / ks;
    const int d0 = dg << 2, o0 = ng << 6, b0 = bq << 5;
    const int dme = d0 + wv_;
    const int c_base = ksid * TS;                  // in 16-c chunks
    const unsigned short* Ab = Ain + (2*dme + (g>>1))*32768 + (b0 + mr)*256 + (g&1)*8;
    const unsigned short* Wb = WT + (size_t)((o0 + mr)*dl + dme)*32 + g*8;
    const int WSTEP = dl << 13;                    // 256*dl*32 shorts per c-chunk
    const int WNB   = dl << 9;                     // 16*dl*32 shorts per n-tile

    floatx4 acc[2][4];
    #pragma unroll
    for (int m = 0; m < 2; ++m)
        #pragma unroll
        for (int nb = 0; nb < 4; ++nb)
            acc[m][nb] = (floatx4){0.f,0.f,0.f,0.f};

    shortx8 a0, a1, na0, na1;                      // A cur/next (named: no alloca)
    shortx8 w0, w1, w2, w3, nw0, nw1, nw2, nw3;    // W cur/next

#define LA(x0_,x1_,ci_) do { \
    const unsigned short* _p = Ab + (ci_)*16; \
    x0_ = *(const shortx8*)(_p); \
    x1_ = *(const shortx8*)(_p + 4096); \
} while(0)
#define LW(y0_,y1_,y2_,y3_,ci_) do { \
    const unsigned short* _p = Wb + (size_t)(ci_)*WSTEP; \
    y0_ = *(const shortx8*)(_p); \
    y1_ = *(const shortx8*)(_p + WNB); \
    y2_ = *(const shortx8*)(_p + 2*WNB); \
    y3_ = *(const shortx8*)(_p + 3*WNB); \
} while(0)

    LA(a0, a1, c_base);
    LW(w0, w1, w2, w3, c_base);
    for (int s = 0; s < TS; ++s){
        if (s + 1 < TS){
            LA(na0, na1, c_base + s + 1);
            LW(nw0, nw1, nw2, nw3, c_base + s + 1);
        }
        acc[0][0] = __builtin_amdgcn_mfma_f32_16x16x32_bf16(a0, w0, acc[0][0], 0,0,0);
        acc[0][1] = __builtin_amdgcn_mfma_f32_16x16x32_bf16(a0, w1, acc[0][1], 0,0,0);
        acc[0][2] = __builtin_amdgcn_mfma_f32_16x16x32_bf16(a0, w2, acc[0][2], 0,0,0);
        acc[0][3] = __builtin_amdgcn_mfma_f32_16x16x32_bf16(a0, w3, acc[0][3], 0,0,0);
        acc[1][0] = __builtin_amdgcn_mfma_f32_16x16x32_bf16(a1, w0, acc[1][0], 0,0,0);
        acc[1][1] = __builtin_amdgcn_mfma_f32_16x16x32_bf16(a1, w1, acc[1][1], 0,0,0);
        acc[1][2] = __builtin_amdgcn_mfma_f32_16x16x32_bf16(a1, w2, acc[1][2], 0,0,0);
        acc[1][3] = __builtin_amdgcn_mfma_f32_16x16x32_bf16(a1, w3, acc[1][3], 0,0,0);
        if (s + 1 < TS){
            a0 = na0; a1 = na1;
            w0 = nw0; w1 = nw1; w2 = nw2; w3 = nw3;
        }
    }
#undef LA
#undef LW
    // epilogue: D row=g*4+r -> b, col=mr -> o
    const size_t pofs = PARTIAL ? ((size_t)ksid * ((size_t)dl << 15)) : 0;
    #pragma unroll
    for (int m = 0; m < 2; ++m)
        #pragma unroll
        for (int nb = 0; nb < 4; ++nb)
            #pragma unroll
            for (int r = 0; r < 4; ++r){
                const int bb = b0 + m*16 + g*4 + r;
                const int oc = o0 + nb*16 + mr;
                if (PARTIAL)
                    ((float*)out)[pofs + (size_t)(dme*128 + bb)*256 + oc] = acc[m][nb][r];
                else
                    ((unsigned short*)out)[dme*32768 + bb*256 + oc] =
                        f2bf(fmaxf(acc[m][nb][r], 0.f) * 0.0625f);
            }
}

// ---------------------------------------------------------------------------
// R7 main layer (FALLBACK when WS too small for WT) — unchanged, verified.
template<bool WBF, bool PARTIAL>
__device__ __forceinline__ void layer_main_impl(const unsigned short* __restrict__ Ain,
        const void* __restrict__ wv, void* __restrict__ out, int dl, int ks,
        unsigned short* __restrict__ Wt0, unsigned short* __restrict__ Wt1){
    const int tid  = threadIdx.x;
    const int lane = tid & 63, wv_ = tid >> 6;
    const int g = lane >> 4, mr = lane & 15;
    const int nd = dl >> 2;
    int dg, ng, mh, ksid;
    {
        const int bi = blockIdx.x;
        const int G  = gridDim.x;
        if (nd >= 2 && (G & 127) == 0){
            const int x = bi & 7, j = (bi >> 3) & 15, gg = bi >> 6;
            const int pid = gg*8 + x;
            const int nd2 = nd >> 1;
            dg   = (pid % nd2)*2 + (j & 1);
            ng   = (j >> 1) & 3;
            mh   = j >> 3;
            ksid = pid / nd2;
        } else {
            dg = bi % nd; const int r = bi / nd;
            ng = r & 3; mh = (r >> 2) & 1; ksid = r >> 3;
        }
    }
    const int TS = 16 / ks;
    const int d0 = dg << 2;
    const int o0 = ng << 6;
    const int b0 = mh << 6;
    const int dme = d0 + wv_;
    const float* wF = (const float*)wv;
    const unsigned short* wB = (const unsigned short*)wv;
    const int cl  = tid & 15;
    const int ooB = tid >> 4;
    const int ws0 = (((o0 + ooB      )*256 + cl)*dl + d0)*2;
    const int ws1 = (((o0 + ooB + 16 )*256 + cl)*dl + d0)*2;
    const int ws2 = (((o0 + ooB + 32 )*256 + cl)*dl + d0)*2;
    const int ws3 = (((o0 + ooB + 48 )*256 + cl)*dl + d0)*2;
    const int wcstep = 32*dl;
    const unsigned short* Ab = Ain + (2*dme + (g>>1))*32768 + (b0 + mr)*256 + (g&1)*8;
    const int c_base = ksid*TS;

    floatx4 acc[4][4];
    #pragma unroll
    for (int m = 0; m < 4; ++m)
        #pragma unroll
        for (int nb = 0; nb < 4; ++nb)
            acc[m][nb] = (floatx4){0.f,0.f,0.f,0.f};

    shortx8 a0, a1, a2, a3;
    shortx8 n0, n1, n2, n3;
    uint4  u0, u1, u2, u3;
    float4 wa0, wa1, wa2, wa3;
    float4 wb0, wb1, wb2, wb3;

#define LOADA4(d0_,d1_,d2_,d3_,s_) do { \
    const unsigned short* _p = Ab + ((c_base + (s_)) << 4); \
    d0_ = *(const shortx8*)(_p);          \
    d1_ = *(const shortx8*)(_p + 4096);   \
    d2_ = *(const shortx8*)(_p + 8192);   \
    d3_ = *(const shortx8*)(_p + 12288);  \
} while(0)
#define LOADW(s_) do { \
    const int _c = (c_base + (s_)) * wcstep; \
    if (WBF){ \
        u0 = *(const uint4*)(wB + ws0 + _c); \
        u1 = *(const uint4*)(wB + ws1 + _c); \
        u2 = *(const uint4*)(wB + ws2 + _c); \
        u3 = *(const uint4*)(wB + ws3 + _c); \
    } else { \
        wa0 = *(const float4*)(wF + ws0 + _c); wb0 = *(const float4*)(wF + ws0 + _c + 4); \
        wa1 = *(const float4*)(wF + ws1 + _c); wb1 = *(const float4*)(wF + ws1 + _c + 4); \
        wa2 = *(const float4*)(wF + ws2 + _c); wb2 = *(const float4*)(wF + ws2 + _c + 4); \
        wa3 = *(const float4*)(wF + ws3 + _c); wb3 = *(const float4*)(wF + ws3 + _c + 4); \
    } \
} while(0)
#define STW_RR(Wt_, uu_, fa_, fb_, oo_) do { \
    unsigned short w0_,w1_,w2_,w3_,w4_,w5_,w6_,w7_; \
    if (WBF){ const unsigned short* _pu = (const unsigned short*)&(uu_); \
        w0_=_pu[0]; w1_=_pu[1]; w2_=_pu[2]; w3_=_pu[3]; w4_=_pu[4]; w5_=_pu[5]; w6_=_pu[6]; w7_=_pu[7]; \
    } else { \
        w0_=f2bf((fa_).x); w1_=f2bf((fa_).y); w2_=f2bf((fa_).z); w3_=f2bf((fa_).w); \
        w4_=f2bf((fb_).x); w5_=f2bf((fb_).y); w6_=f2bf((fb_).z); w7_=f2bf((fb_).w); \
    } \
    (Wt_)[((0*64) + (oo_))*40 +  0 + cl] = w0_; \
    (Wt_)[((0*64) + (oo_))*40 + 16 + cl] = w1_; \
    (Wt_)[((1*64) + (oo_))*40 +  0 + cl] = w2_; \
    (Wt_)[((1*64) + (oo_))*40 + 16 + cl] = w3_; \
    (Wt_)[((2*64) + (oo_))*40 +  0 + cl] = w4_; \
    (Wt_)[((2*64) + (oo_))*40 + 16 + cl] = w5_; \
    (Wt_)[((3*64) + (oo_))*40 +  0 + cl] = w6_; \
    (Wt_)[((3*64) + (oo_))*40 + 16 + cl] = w7_; \
} while(0)
#define STOREW(Wt_) do { \
    STW_RR(Wt_, u0, wa0, wb0, ooB      ); \
    STW_RR(Wt_, u1, wa1, wb1, ooB + 16 ); \
    STW_RR(Wt_, u2, wa2, wb2, ooB + 32 ); \
    STW_RR(Wt_, u3, wa3, wb3, ooB + 48 ); \
} while(0)

    LOADW(0);
    LOADA4(a0, a1, a2, a3, 0);
    STOREW(Wt0);
    for (int s = 0; s < TS; ++s){
        __syncthreads();
        if (s + 1 < TS){
            LOADA4(n0, n1, n2, n3, s + 1);
            LOADW(s + 1);
        }
        const unsigned short* Wr = (s & 1) ? Wt1 : Wt0;
        shortx8 br0 = *(const shortx8*)(Wr + (wv_*64 +  0 + mr)*40 + g*8);
        shortx8 br1 = *(const shortx8*)(Wr + (wv_*64 + 16 + mr)*40 + g*8);
        shortx8 br2 = *(const shortx8*)(Wr + (wv_*64 + 32 + mr)*40 + g*8);
        shortx8 br3 = *(const shortx8*)(Wr + (wv_*64 + 48 + mr)*40 + g*8);
#define MFMA_ROW(m_, ar_) \
        acc[m_][0] = __builtin_amdgcn_mfma_f32_16x16x32_bf16(ar_, br0, acc[m_][0], 0,0,0); \
        acc[m_][1] = __builtin_amdgcn_mfma_f32_16x16x32_bf16(ar_, br1, acc[m_][1], 0,0,0); \
        acc[m_][2] = __builtin_amdgcn_mfma_f32_16x16x32_bf16(ar_, br2, acc[m_][2], 0,0,0); \
        acc[m_][3] = __builtin_amdgcn_mfma_f32_16x16x32_bf16(ar_, br3, acc[m_][3], 0,0,0);
        MFMA_ROW(0, a0)
        MFMA_ROW(1, a1)
        MFMA_ROW(2, a2)
        MFMA_ROW(3, a3)
#undef MFMA_ROW
        if (s + 1 < TS){
            STOREW((s & 1) ? Wt0 : Wt1);
            a0 = n0; a1 = n1; a2 = n2; a3 = n3;
        }
    }
#undef LOADA4
#undef LOADW
#undef STW_RR
#undef STOREW
    const size_t pofs = PARTIAL ? ((size_t)ksid * ((size_t)dl << 15)) : 0;
    #pragma unroll
    for (int m = 0; m < 4; ++m)
        #pragma unroll
        for (int nb = 0; nb < 4; ++nb)
            #pragma unroll
            for (int r = 0; r < 4; ++r){
                const int bb = b0 + m*16 + g*4 + r;
                const int oc = o0 + nb*16 + mr;
                if (PARTIAL)
                    ((float*)out)[pofs + (size_t)(dme*128 + bb)*256 + oc] = acc[m][nb][r];
                else
                    ((unsigned short*)out)[dme*32768 + bb*256 + oc] =
                        f2bf(fmaxf(acc[m][nb][r], 0.f) * 0.0625f);
            }
}
template<bool PARTIAL>
__global__ __launch_bounds__(256,2) void layer_main_k(const int* __restrict__ flag,
        const unsigned short* __restrict__ Ain, const void* __restrict__ wv,
        void* __restrict__ out, int dl, int ks){
    __shared__ unsigned short Wt[2][4*64*40];
    if (*flag) layer_main_impl<true,  PARTIAL>(Ain, wv, out, dl, ks, Wt[0], Wt[1]);
    else       layer_main_impl<false, PARTIAL>(Ain, wv, out, dl, ks, Wt[0], Wt[1]);
}

// ---------------------------------------------------------------------------
// Tail layers (dl<=2): unchanged from R7 (partial stores), verified.
template<bool WBF>
__device__ __forceinline__ void tail_impl(const unsigned short* __restrict__ Ain,
        const void* __restrict__ wv, float* __restrict__ outP, int dl, int ksplit){
    int id = blockIdx.x;
    int d = id % dl; int t2 = id / dl;
    int ob = t2 & 3; int ksid = t2 >> 2;
    const int KSEG = 512 / ksplit;
    const int k0s = ksid * KSEG;
    const int lane = threadIdx.x & 63, wv2 = threadIdx.x >> 6;
    const int mr = lane & 15, kg = lane >> 4;
    const float* wF = (const float*)wv;
    const unsigned short* wB = (const unsigned short*)wv;
    floatx4 acc[2][4];
    #pragma unroll
    for (int mi = 0; mi < 2; ++mi)
        #pragma unroll
        for (int ni = 0; ni < 4; ++ni) acc[mi][ni] = (floatx4){0.f,0.f,0.f,0.f};
    for (int k0 = k0s; k0 < k0s + KSEG; k0 += 32){
        int c0 = (k0 >> 1) + kg*4;
        shortx8 af[2];
        #pragma unroll
        for (int mi = 0; mi < 2; ++mi){
            int b = wv2*32 + mi*16 + mr;
            #pragma unroll
            for (int cc = 0; cc < 4; ++cc){
                af[mi][2*cc]   = (short)Ain[(2*d)*32768   + b*256 + c0 + cc];
                af[mi][2*cc+1] = (short)Ain[(2*d+1)*32768 + b*256 + c0 + cc];
            }
        }
        shortx8 bf_[4];
        #pragma unroll
        for (int ni = 0; ni < 4; ++ni){
            int o = ob*64 + ni*16 + mr;
            int base = ((o*256 + c0)*dl + d)*2;
            #pragma unroll
            for (int cc = 0; cc < 4; ++cc){
                if (WBF){
                    unsigned int u = *(const unsigned int*)(wB + base);
                    bf_[ni][2*cc]   = (short)(u & 0xFFFFu);
                    bf_[ni][2*cc+1] = (short)(u >> 16);
                } else {
                    bf_[ni][2*cc]   = (short)f2bf(wF[base]);
                    bf_[ni][2*cc+1] = (short)f2bf(wF[base+1]);
                }
                base += 2*dl;
            }
        }
        #pragma unroll
        for (int mi = 0; mi < 2; ++mi)
            #pragma unroll
            for (int ni = 0; ni < 4; ++ni)
                acc[mi][ni] = __builtin_amdgcn_mfma_f32_16x16x32_bf16(af[mi], bf_[ni], acc[mi][ni], 0,0,0);
    }
    const size_t pofs = (size_t)ksid * ((size_t)dl << 15);
    #pragma unroll
    for (int mi = 0; mi < 2; ++mi)
        #pragma unroll
        for (int ni = 0; ni < 4; ++ni)
            #pragma unroll
            for (int r = 0; r < 4; ++r){
                int b = wv2*32 + mi*16 + kg*4 + r;
                int o = ob*64 + ni*16 + mr;
                outP[pofs + (size_t)(d*128 + b)*256 + o] = acc[mi][ni][r];
            }
}
__global__ __launch_bounds__(256) void tail_k(const int* __restrict__ flag,
        const unsigned short* __restrict__ Ain, const void* __restrict__ wv,
        float* __restrict__ outP, int dl, int ksplit){
    if (*flag) tail_impl<true >(Ain, wv, outP, dl, ksplit);
    else       tail_impl<false>(Ain, wv, outP, dl, ksplit);
}

// ---------------------------------------------------------------------------
// Finalize: A_{l+1}[i] = bf16(relu(sum_{k<ks} P[k][i]) / 16)
__global__ __launch_bounds__(256) void fin_kernel(const float* __restrict__ P,
        unsigned short* __restrict__ A, int n, int ks){
    int i = (blockIdx.x*256 + threadIdx.x)*4;
    if (i + 3 < n){
        float4 v = *(const float4*)(P + i);
        for (int k = 1; k < ks; ++k){
            float4 w = *(const float4*)(P + (size_t)k*n + i);
            v.x += w.x; v.y += w.y; v.z += w.z; v.w += w.w;
        }
        unsigned short r0 = f2bf(fmaxf(v.x,0.f)*0.0625f);
        unsigned short r1 = f2bf(fmaxf(v.y,0.f)*0.0625f);
        unsigned short r2 = f2bf(fmaxf(v.z,0.f)*0.0625f);
        unsigned short r3 = f2bf(fmaxf(v.w,0.f)*0.0625f);
        unsigned int lo = (unsigned int)r0 | ((unsigned int)r1 << 16);
        unsigned int hi = (unsigned int)r2 | ((unsigned int)r3 << 16);
        uint2 u; u.x = lo; u.y = hi;
        *(uint2*)(A + i) = u;
    }
}

// ---------------------------------------------------------------------------
// Epilogue: out[b,o] = (sum_h relu(sum_k P9[k][b][h])/16 * beta[h,o]) / 256
template<bool BF>
__device__ __forceinline__ void epi_impl(const float* __restrict__ P9, const void* __restrict__ beta,
                                         void* __restrict__ out){
    int b = blockIdx.x;
    int lane = threadIdx.x;
    float accv[10];
    #pragma unroll
    for (int o = 0; o < 10; ++o) accv[o] = 0.f;
    for (int h = lane; h < 256; h += 64){
        float s = 0.f;
        #pragma unroll
        for (int k = 0; k < 16; ++k)
            s += P9[(size_t)k*32768 + b*256 + h];
        float y = fmaxf(s, 0.f) * 0.0625f;
        #pragma unroll
        for (int o = 0; o < 10; ++o){
            float be = BF ? bf2f(((const unsigned short*)beta)[h*10 + o])
                          : ((const float*)beta)[h*10 + o];
            accv[o] += y * be;
        }
    }
    #pragma unroll
    for (int off = 32; off > 0; off >>= 1){
        #pragma unroll
        for (int o = 0; o < 10; ++o)
            accv[o] += __shfl_down(accv[o], off, 64);
    }
    if (lane == 0){
        #pragma unroll
        for (int o = 0; o < 10; ++o){
            float v = accv[o] * (1.f/256.f);
            if (BF) ((unsigned short*)out)[b*10 + o] = f2bf(v);
            else    ((float*)out)[b*10 + o] = v;
        }
    }
}
__global__ void epi_kernel(const int* __restrict__ flag, const float* __restrict__ P9,
                           const void* __restrict__ beta, void* __restrict__ out){
    if (*flag) epi_impl<true>(P9, beta, out);
    else       epi_impl<false>(P9, beta, out);
}

// ---------------------------------------------------------------------------
extern "C" void kernel_launch(void* const* d_in, const int* in_sizes, int n_in,
                              void* d_out, int out_size, void* d_ws, size_t ws_size,
                              hipStream_t stream) {
    (void)in_sizes; (void)n_in; (void)out_size;
    char* wsb = (char*)d_ws;
    int* flag = (int*)wsb;
    unsigned short* A1 = (unsigned short*)(wsb + 512);
    float* P = (float*)(wsb + 512);
    unsigned short* A2 = (unsigned short*)(wsb + 512 + 33554432);
    unsigned short* A3 = A2;
    unsigned short* A4 = A3 + 4194304;
    unsigned short* A5 = A4 + 2097152;
    unsigned short* A6 = A5 + 1048576;
    unsigned short* A7 = A6 + 524288;
    unsigned short* A8 = A7 + 262144;
    unsigned short* A9 = A8 + 131072;
    // WT scratch after the legacy 50.33-MB layout; adaptive per layer on fit.
    const size_t BASE = 512 + 33554432 + 16777216;
    unsigned short* WTb = (unsigned short*)(wsb + BASE);
    const size_t avail = (ws_size > BASE) ? (ws_size - BASE) : 0;
    // WT_l bytes = 16*256*dl*32*2 = dl*262144
    #define CANT(dl_) ((size_t)(dl_)*262144 <= avail)

    probe_kernel<<<1, 256, 0, stream>>>((const unsigned int*)d_in[0], flag);
    l0_kernel<<<512, 256, 0, stream>>>(flag, d_in[0], d_in[1], A1);

    // l1: dl=256, ks=1 (bf16 direct out)
    if (CANT(256)){
        tr_k<<<4096, 256, 0, stream>>>(flag, d_in[2], WTb, 256);
        layer_t_k<false><<<1024, 256, 0, stream>>>(A1, WTb, A2, 256, 1);
    } else {
        layer_main_k<false><<<512, 256, 0, stream>>>(flag, A1, d_in[2], A2, 256, 1);
    }
    // l2: dl=128, ks=2
    if (CANT(128)){
        tr_k<<<4096, 256, 0, stream>>>(flag, d_in[3], WTb, 128);
        layer_t_k<true ><<<1024, 256, 0, stream>>>(A2, WTb, P, 128, 2);
    } else {
        layer_main_k<true ><<<512, 256, 0, stream>>>(flag, A2, d_in[3], P, 128, 2);
    }
    fin_kernel<<<4096, 256, 0, stream>>>(P, A3, 4194304, 2);
    // l3: dl=64, ks=4
    if (CANT(64)){
        tr_k<<<4096, 256, 0, stream>>>(flag, d_in[4], WTb, 64);
        layer_t_k<true ><<<1024, 256, 0, stream>>>(A3, WTb, P, 64, 4);
    } else {
        layer_main_k<true ><<<512, 256, 0, stream>>>(flag, A3, d_in[4], P, 64, 4);
    }
    fin_kernel<<<2048, 256, 0, stream>>>(P, A4, 2097152, 4);
    // l4: dl=32, ks=8
    if (CANT(32)){
        tr_k<<<4096, 256, 0, stream>>>(flag, d_in[5], WTb, 32);
        layer_t_k<true ><<<1024, 256, 0, stream>>>(A4, WTb, P, 32, 8);
    } else {
        layer_main_k<true ><<<512, 256, 0, stream>>>(flag, A4, d_in[5], P, 32, 8);
    }
    fin_kernel<<<1024, 256, 0, stream>>>(P, A5, 1048576, 8);
    // l5: dl=16, ks=16
    if (CANT(16)){
        tr_k<<<4096, 256, 0, stream>>>(flag, d_in[6], WTb, 16);
        layer_t_k<true ><<<1024, 256, 0, stream>>>(A5, WTb, P, 16, 16);
    } else {
        layer_main_k<true ><<<512, 256, 0, stream>>>(flag, A5, d_in[6], P, 16, 16);
    }
    fin_kernel<<<512, 256, 0, stream>>>(P, A6, 524288, 16);
    // l6: dl=8, ks=16
    if (CANT(8)){
        tr_k<<<4096, 256, 0, stream>>>(flag, d_in[7], WTb, 8);
        layer_t_k<true ><<<512, 256, 0, stream>>>(A6, WTb, P, 8, 16);
    } else {
        layer_main_k<true ><<<256, 256, 0, stream>>>(flag, A6, d_in[7], P, 8, 16);
    }
    fin_kernel<<<256, 256, 0, stream>>>(P, A7, 262144, 16);
    // l7: dl=4, ks=16
    if (CANT(4)){
        tr_k<<<4096, 256, 0, stream>>>(flag, d_in[8], WTb, 4);
        layer_t_k<true ><<<256, 256, 0, stream>>>(A7, WTb, P, 4, 16);
    } else {
        layer_main_k<true ><<<128, 256, 0, stream>>>(flag, A7, d_in[8], P, 4, 16);
    }
    fin_kernel<<<128, 256, 0, stream>>>(P, A8, 131072, 16);
    #undef CANT
    // tails unchanged
    tail_k<<<128, 256, 0, stream>>>(flag, A8, d_in[9], P, 2, 16);
    fin_kernel<<<64, 256, 0, stream>>>(P, A9, 65536, 16);
    tail_k<<<64, 256, 0, stream>>>(flag, A9, d_in[10], P, 1, 16);
    epi_kernel<<<128, 64, 0, stream>>>(flag, P, d_in[11], d_out);
}